// Round 1
// 1254.610 us; speedup vs baseline: 1.7880x; 1.7880x over previous
//
#include <hip/hip_runtime.h>
#include <math.h>
#include <stdint.h>

// dims
#define BB   2
#define SS   1024
#define DD   1024
#define HH   16
#define DHH  64
#define DFFD 4096
#define LL   2
#define VV   32000
#define GSZ  128
#define BSR  (BB*SS)   // 2048 rows
constexpr float EPS = 1e-6f;

typedef unsigned short ushort_t;
typedef __bf16 bf16x8 __attribute__((ext_vector_type(8)));
typedef short  short8 __attribute__((ext_vector_type(8)));
typedef unsigned short ushort8v __attribute__((ext_vector_type(8)));
typedef float  f32x4  __attribute__((ext_vector_type(4)));

__device__ inline ushort_t f2bf(float f) {
    unsigned int u = __builtin_bit_cast(unsigned int, f);
    unsigned int r = u + 0x7fffu + ((u >> 16) & 1u);
    return (ushort_t)(r >> 16);
}
__device__ inline float bf2f(ushort_t u) {
    unsigned int x = ((unsigned int)u) << 16;
    return __builtin_bit_cast(float, x);
}

#define GL2L(g, l) __builtin_amdgcn_global_load_lds( \
    (const __attribute__((address_space(1))) void*)(g), \
    (__attribute__((address_space(3))) void*)(l), 16, 0, 0)

// ---------------- dequant: W[i] = bf16(T[i] * S[i/128]) ----------------
__global__ __launch_bounds__(256) void k_dequant(const int* __restrict__ T,
                                                 const float* __restrict__ S,
                                                 ushort_t* __restrict__ W) {
    int i = (blockIdx.x * 256 + threadIdx.x) * 4;
    int4 t = *(const int4*)(T + i);
    float s = S[i >> 7];
    ushort4 w;
    w.x = f2bf((float)t.x * s); w.y = f2bf((float)t.y * s);
    w.z = f2bf((float)t.z * s); w.w = f2bf((float)t.w * s);
    *(ushort4*)(W + i) = w;
}

// ---------------- embedding: x[row,:] = t[id,:] * s[id, d/128] (fp32) ----------------
__global__ __launch_bounds__(256) void k_embed(const int* __restrict__ ids,
                                               const int* __restrict__ t,
                                               const float* __restrict__ s,
                                               float* __restrict__ x) {
    int row = blockIdx.x;
    int id  = ids[row];
    for (int d = threadIdx.x; d < DD; d += 256) {
        x[(size_t)row * DD + d] =
            (float)t[(size_t)id * DD + d] * s[id * (DD / GSZ) + (d >> 7)];
    }
}

// ---------------- rmsnorm: o = bf16(x * rsqrt(mean(x^2)+eps) * w) ----------------
__global__ __launch_bounds__(256) void k_rmsnorm(const float* __restrict__ x,
                                                 const float* __restrict__ w,
                                                 ushort_t* __restrict__ o) {
    int row = blockIdx.x;
    const float* xr = x + (size_t)row * DD;
    float ss = 0.f;
    for (int d = threadIdx.x; d < DD; d += 256) { float v = xr[d]; ss += v * v; }
    __shared__ float sm[4];
    for (int off = 32; off > 0; off >>= 1) ss += __shfl_down(ss, off, 64);
    if ((threadIdx.x & 63) == 0) sm[threadIdx.x >> 6] = ss;
    __syncthreads();
    float tot = sm[0] + sm[1] + sm[2] + sm[3];
    float inv = rsqrtf(tot / DD + EPS);
    for (int d = threadIdx.x; d < DD; d += 256)
        o[(size_t)row * DD + d] = f2bf(xr[d] * inv * w[d]);
}

// ---------------- bf16 MFMA GEMM: C[M,N] = A[M,K] @ W[N,K]^T ----------------
// m97 structure: 128x128 tile, BK=32, 256 thr = 4 waves, each wave 64x64 via
// 4x4 grid of mfma_f32_16x16x32_bf16. global_load_lds width=16 staging.
// MODE: 0 = store f32, 1 = add f32, 2 = swiglu(read Gf, write bf16), 3 = store bf16
template <int MODE>
__global__ __launch_bounds__(256) void gemm_bf16(const ushort_t* __restrict__ A,
                                                 const ushort_t* __restrict__ W,
                                                 float* __restrict__ Cf,
                                                 ushort_t* __restrict__ Cb,
                                                 const float* __restrict__ Gf,
                                                 int M, int N, int K) {
    __shared__ ushort_t As[128 * 32];
    __shared__ ushort_t Bs[128 * 32];
    const int tid  = threadIdx.x;
    const int wave = tid >> 6, lane = tid & 63;
    const int wm = wave >> 1, wn = wave & 1;
    const int i0 = blockIdx.y * 128, o0 = blockIdx.x * 128;

    f32x4 acc[4][4] = {};

    // staging: per wave, 2 calls for A + 2 for B; call covers 16 rows x 32 cols
    const int srow = wave * 32 + (lane >> 2);
    const int scol = (lane & 3) * 8;
    const ushort_t* aG0 = A + (size_t)(i0 + srow) * K + scol;
    const ushort_t* aG1 = aG0 + (size_t)16 * K;
    const ushort_t* bG0 = W + (size_t)(o0 + srow) * K + scol;
    const ushort_t* bG1 = bG0 + (size_t)16 * K;
    ushort_t* aL0 = As + wave * 1024;
    ushort_t* aL1 = aL0 + 512;
    ushort_t* bL0 = Bs + wave * 1024;
    ushort_t* bL1 = bL0 + 512;

    // fragment read base: A[m=lane&15][k=(lane>>4)*8 + j]
    const ushort_t* ap = As + (wm * 64 + (lane & 15)) * 32 + (lane >> 4) * 8;
    const ushort_t* bp = Bs + (wn * 64 + (lane & 15)) * 32 + (lane >> 4) * 8;

    for (int k0 = 0; k0 < K; k0 += 32) {
        __syncthreads();
        GL2L(aG0 + k0, aL0);
        GL2L(aG1 + k0, aL1);
        GL2L(bG0 + k0, bL0);
        GL2L(bG1 + k0, bL1);
        __syncthreads();
        bf16x8 av[4], bv[4];
#pragma unroll
        for (int t = 0; t < 4; ++t) {
            av[t] = __builtin_bit_cast(bf16x8, *(const short8*)(ap + t * 512));
            bv[t] = __builtin_bit_cast(bf16x8, *(const short8*)(bp + t * 512));
        }
#pragma unroll
        for (int mt = 0; mt < 4; ++mt)
#pragma unroll
            for (int nt = 0; nt < 4; ++nt)
                acc[mt][nt] = __builtin_amdgcn_mfma_f32_16x16x32_bf16(
                    av[mt], bv[nt], acc[mt][nt], 0, 0, 0);
    }

    // epilogue: C/D layout col=lane&15, row=(lane>>4)*4+reg
    const int r0 = wm * 64 + (lane >> 4) * 4;
    const int c0 = wn * 64 + (lane & 15);
#pragma unroll
    for (int mt = 0; mt < 4; ++mt) {
#pragma unroll
        for (int r = 0; r < 4; ++r) {
            const size_t row = i0 + r0 + mt * 16 + r;
#pragma unroll
            for (int nt = 0; nt < 4; ++nt) {
                const size_t col = o0 + c0 + nt * 16;
                const size_t idx = row * (size_t)N + col;
                float v = acc[mt][nt][r];
                if (MODE == 0) {
                    Cf[idx] = v;
                } else if (MODE == 1) {
                    Cf[idx] += v;
                } else if (MODE == 2) {
                    float gv = Gf[idx];
                    Cb[idx] = f2bf(gv / (1.f + __expf(-gv)) * v);
                } else {
                    Cb[idx] = f2bf(v);
                }
            }
        }
    }
}

// ---------------- flash attention (MFMA): one block per (b,h,64-row q-tile) ----
// qkv: [BSR, 3072] fused (q | k | v) bf16. hn: [BSR, D] bf16. out: [BSR, D] bf16.
// 4 waves; wave wm owns q rows [qt*64+wm*16, +16). Per 64-key tile:
//   S = Q@K^T via mfma_16x16x32 (A=Q rows, B=K rows), online softmax in-register
//   (C-frag row lives across 16 lanes -> shfl_xor reduce), P->bf16 via per-wave
//   LDS bounce to A-frag layout, O += P@V with B = V^T (transposed on staging).
// LDS pitch 72 ushorts (144B = 16B-aligned rows, uniform bank spread for b128).
__global__ __launch_bounds__(256) void k_fattn(const ushort_t* __restrict__ qkv,
                                               const ushort_t* __restrict__ hn,
                                               const float* __restrict__ alpha,
                                               ushort_t* __restrict__ out) {
    __shared__ ushort_t Ks[64][72];
    __shared__ ushort_t Vt[64][72];
    __shared__ ushort_t Ps[4][16][72];

    const int bid = blockIdx.x;
    const int bh  = bid & 31;           // b*16 + h
    const int qt  = 15 - (bid >> 5);    // heavy q-tiles dispatched first
    const int hh  = bh & 15;
    const int b   = bh >> 4;
    const int tid = threadIdx.x;
    const int wm  = tid >> 6;
    const int ln  = tid & 63;
    const int m16 = ln & 15;
    const int q4  = ln >> 4;

    const int bS0 = b * SS;
    const int q0  = qt * 64 + wm * 16;  // wave's first q row (local to batch b)

    // Q fragments: A[m=m16][k=(q4)*8+j], k-tiles 0 and 32
    bf16x8 qa0, qa1;
    {
        const ushort_t* qp = qkv + (size_t)(bS0 + q0 + m16) * 3072 + hh * DHH + q4 * 8;
        qa0 = __builtin_bit_cast(bf16x8, *(const ushort8v*)(qp));
        qa1 = __builtin_bit_cast(bf16x8, *(const ushort8v*)(qp + 32));
    }

    f32x4 oacc[4] = {};   // [dh-subtile]; row=q4*4+r, col=dh=dt*16+m16
    float mrow[4] = {-1e30f, -1e30f, -1e30f, -1e30f};
    float lrow[4] = {0.f, 0.f, 0.f, 0.f};

    const int c0a = tid, c1a = tid + 256;       // staging chunks
    const int r0a = c0a >> 3, cc0 = (c0a & 7) * 8;
    const int r1a = c1a >> 3, cc1 = (c1a & 7) * 8;

    for (int t = 0; t <= qt; ++t) {
        __syncthreads();
        {   // ---- stage K tile [64 keys][64 dh] row-major ----
            const size_t kbase = (size_t)(bS0 + t * 64) * 3072 + 1024 + hh * DHH;
            *(ushort8v*)&Ks[r0a][cc0] = *(const ushort8v*)(qkv + kbase + (size_t)r0a * 3072 + cc0);
            *(ushort8v*)&Ks[r1a][cc1] = *(const ushort8v*)(qkv + kbase + (size_t)r1a * 3072 + cc1);
            // ---- stage V tile transposed: Vt[dh][key] ----
            const size_t vbase = (size_t)(bS0 + t * 64) * 3072 + 2048 + hh * DHH;
            ushort8v v0 = *(const ushort8v*)(qkv + vbase + (size_t)r0a * 3072 + cc0);
#pragma unroll
            for (int j = 0; j < 8; ++j) Vt[cc0 + j][r0a] = v0[j];
            ushort8v v1 = *(const ushort8v*)(qkv + vbase + (size_t)r1a * 3072 + cc1);
#pragma unroll
            for (int j = 0; j < 8; ++j) Vt[cc1 + j][r1a] = v1[j];
        }
        __syncthreads();

        // ---- scores: S[16 q][64 key] in 4 C-frags ----
        f32x4 sc[4];
#pragma unroll
        for (int nt = 0; nt < 4; ++nt) {
            bf16x8 kb0 = __builtin_bit_cast(bf16x8, *(const ushort8v*)&Ks[nt * 16 + m16][q4 * 8]);
            bf16x8 kb1 = __builtin_bit_cast(bf16x8, *(const ushort8v*)&Ks[nt * 16 + m16][32 + q4 * 8]);
            f32x4 z = {};
            z = __builtin_amdgcn_mfma_f32_16x16x32_bf16(qa0, kb0, z, 0, 0, 0);
            sc[nt] = __builtin_amdgcn_mfma_f32_16x16x32_bf16(qa1, kb1, z, 0, 0, 0);
        }

        // ---- online softmax (per r: row = q4*4 + r across 16 lanes) ----
        const bool diag = (t == qt);
#pragma unroll
        for (int r = 0; r < 4; ++r) {
            float s0 = sc[0][r] * 0.125f;
            float s1 = sc[1][r] * 0.125f;
            float s2 = sc[2][r] * 0.125f;
            float s3 = sc[3][r] * 0.125f;
            if (diag) {
                const int rl = wm * 16 + q4 * 4 + r;   // row local to 64-block
                if (m16      > rl) s0 = -1e30f;
                if (m16 + 16 > rl) s1 = -1e30f;
                if (m16 + 32 > rl) s2 = -1e30f;
                if (m16 + 48 > rl) s3 = -1e30f;
            }
            float tm = fmaxf(fmaxf(s0, s1), fmaxf(s2, s3));
            tm = fmaxf(tm, __shfl_xor(tm, 1, 64));
            tm = fmaxf(tm, __shfl_xor(tm, 2, 64));
            tm = fmaxf(tm, __shfl_xor(tm, 4, 64));
            tm = fmaxf(tm, __shfl_xor(tm, 8, 64));
            const float mnew = fmaxf(mrow[r], tm);
            const float corr = __expf(mrow[r] - mnew);
            const float e0 = __expf(s0 - mnew);
            const float e1 = __expf(s1 - mnew);
            const float e2 = __expf(s2 - mnew);
            const float e3 = __expf(s3 - mnew);
            float rs = e0 + e1 + e2 + e3;
            rs += __shfl_xor(rs, 1, 64);
            rs += __shfl_xor(rs, 2, 64);
            rs += __shfl_xor(rs, 4, 64);
            rs += __shfl_xor(rs, 8, 64);
            lrow[r] = lrow[r] * corr + rs;
            mrow[r] = mnew;
#pragma unroll
            for (int dt = 0; dt < 4; ++dt) oacc[dt][r] *= corr;
            const int pr = q4 * 4 + r;
            Ps[wm][pr][m16]      = f2bf(e0);
            Ps[wm][pr][m16 + 16] = f2bf(e1);
            Ps[wm][pr][m16 + 32] = f2bf(e2);
            Ps[wm][pr][m16 + 48] = f2bf(e3);
        }

        // ---- O += P @ V : A = P[m=q][k=key], B = Vt[n=dh][k=key] ----
#pragma unroll
        for (int ks = 0; ks < 2; ++ks) {
            bf16x8 pa = __builtin_bit_cast(bf16x8, *(const ushort8v*)&Ps[wm][m16][ks * 32 + q4 * 8]);
#pragma unroll
            for (int dt = 0; dt < 4; ++dt) {
                bf16x8 vb = __builtin_bit_cast(bf16x8, *(const ushort8v*)&Vt[dt * 16 + m16][ks * 32 + q4 * 8]);
                oacc[dt] = __builtin_amdgcn_mfma_f32_16x16x32_bf16(pa, vb, oacc[dt], 0, 0, 0);
            }
        }
    }

    // ---- epilogue: out = o/l + alpha * hn ----
    const float al = alpha[hh];
#pragma unroll
    for (int r = 0; r < 4; ++r) {
        const float inv = 1.f / lrow[r];
        const size_t row = (size_t)(bS0 + q0 + q4 * 4 + r);
#pragma unroll
        for (int dt = 0; dt < 4; ++dt) {
            const size_t idx = row * DD + hh * DHH + dt * 16 + m16;
            out[idx] = f2bf(oacc[dt][r] * inv + al * bf2f(hn[idx]));
        }
    }
}

extern "C" void kernel_launch(void* const* d_in, const int* in_sizes, int n_in,
                              void* d_out, int out_size, void* d_ws, size_t ws_size,
                              hipStream_t stream) {
    const int*   ids   = (const int*)d_in[0];
    const int*   emb_t = (const int*)d_in[1];
    const float* emb_s = (const float*)d_in[2];
    const int*   qt    = (const int*)d_in[3];
    const float* qs    = (const float*)d_in[4];
    const int*   kt    = (const int*)d_in[5];
    const float* ks    = (const float*)d_in[6];
    const int*   vt    = (const int*)d_in[7];
    const float* vs    = (const float*)d_in[8];
    const int*   ot    = (const int*)d_in[9];
    const float* os    = (const float*)d_in[10];
    const int*   gatet = (const int*)d_in[11];
    const float* gates = (const float*)d_in[12];
    const int*   upt   = (const int*)d_in[13];
    const float* ups   = (const float*)d_in[14];
    const int*   downt = (const int*)d_in[15];
    const float* downs = (const float*)d_in[16];
    const float* wa    = (const float*)d_in[17];
    const float* wm    = (const float*)d_in[18];
    const float* alpha = (const float*)d_in[19];
    const float* wf    = (const float*)d_in[20];
    const int*   headt = (const int*)d_in[21];
    const float* heads = (const float*)d_in[22];

    // ---- workspace layout (byte offsets; region [0,75MB) is time-aliased) ----
    const size_t MB = 1ull << 20;
    char* wsb = (char*)d_ws;
    ushort_t* wbuf = (ushort_t*)(wsb);            // <= 65.6MB
    float*    g    = (float*)   (wsb + 24 * MB);  // 33.6MB
    ushort_t* gb   = (ushort_t*)(wsb + 58 * MB);  // 16.8MB
    float*    x    = (float*)   (wsb + 75 * MB);  // 8.4MB
    ushort_t* h    = (ushort_t*)(wsb + 84 * MB);  // 4.2MB
    ushort_t* qkvb = (ushort_t*)(wsb + 89 * MB);  // 12.6MB  [BSR, 3072]
    ushort_t* ao   = (ushort_t*)(wsb + 102 * MB); // 4.2MB   ends ~106.2MB

    const size_t wDD = (size_t)DD * DD;       // 1M elems
    const size_t sDD = wDD / GSZ;
    const size_t wFD = (size_t)DFFD * DD;     // 4M elems
    const size_t sFD = wFD / GSZ;

    k_embed<<<BSR, 256, 0, stream>>>(ids, emb_t, emb_s, x);

    const dim3 gQKV(3072 / 128, BSR / 128);   // 24 x 16
    const dim3 gD(DD / 128, BSR / 128);       // 8 x 16
    const dim3 gF(DFFD / 128, BSR / 128);     // 32 x 16
    const dim3 gV(VV / 128, BSR / 128);       // 250 x 16

    for (int l = 0; l < LL; ++l) {
        k_rmsnorm<<<BSR, 256, 0, stream>>>(x, wa + l * DD, h);
        // fused QKV weights -> wbuf [3072, 1024]
        k_dequant<<<wDD / 1024, 256, 0, stream>>>(qt + l * wDD, qs + l * sDD, wbuf);
        k_dequant<<<wDD / 1024, 256, 0, stream>>>(kt + l * wDD, ks + l * sDD, wbuf + wDD);
        k_dequant<<<wDD / 1024, 256, 0, stream>>>(vt + l * wDD, vs + l * sDD, wbuf + 2 * wDD);
        gemm_bf16<3><<<gQKV, 256, 0, stream>>>(h, wbuf, nullptr, qkvb, nullptr, BSR, 3072, DD);
        // flash attention: (S/64) q-tiles x B x H = 16 * 32 = 512 blocks
        k_fattn<<<16 * BB * HH, 256, 0, stream>>>(qkvb, h, alpha + l * HH, ao);
        k_dequant<<<wDD / 1024, 256, 0, stream>>>(ot + l * wDD, os + l * sDD, wbuf);
        gemm_bf16<1><<<gD, 256, 0, stream>>>(ao, wbuf, x, nullptr, nullptr, BSR, DD, DD);

        k_rmsnorm<<<BSR, 256, 0, stream>>>(x, wm + l * DD, h);
        k_dequant<<<wFD / 1024, 256, 0, stream>>>(gatet + l * wFD, gates + l * sFD, wbuf);
        gemm_bf16<0><<<gF, 256, 0, stream>>>(h, wbuf, g, nullptr, nullptr, BSR, DFFD, DD);
        k_dequant<<<wFD / 1024, 256, 0, stream>>>(upt + l * wFD, ups + l * sFD, wbuf);
        gemm_bf16<2><<<gF, 256, 0, stream>>>(h, wbuf, nullptr, gb, g, BSR, DFFD, DD);
        k_dequant<<<wFD / 1024, 256, 0, stream>>>(downt + l * wFD, downs + l * sFD, wbuf);
        gemm_bf16<1><<<gD, 256, 0, stream>>>(gb, wbuf, x, nullptr, nullptr, BSR, DD, DFFD);
    }

    k_rmsnorm<<<BSR, 256, 0, stream>>>(x, wf, h);
    k_dequant<<<((size_t)VV * DD) / 1024, 256, 0, stream>>>(headt, heads, wbuf);
    gemm_bf16<0><<<gV, 256, 0, stream>>>(h, wbuf, (float*)d_out, nullptr, nullptr, BSR, VV, DD);
}

// Round 2
// 1216.852 us; speedup vs baseline: 1.8435x; 1.0310x over previous
//
#include <hip/hip_runtime.h>
#include <math.h>
#include <stdint.h>

// dims
#define BB   2
#define SS   1024
#define DD   1024
#define HH   16
#define DHH  64
#define DFFD 4096
#define LL   2
#define VV   32000
#define GSZ  128
#define BSR  (BB*SS)   // 2048 rows
constexpr float EPS = 1e-6f;

typedef unsigned short ushort_t;
typedef __bf16 bf16x8 __attribute__((ext_vector_type(8)));
typedef short  short8 __attribute__((ext_vector_type(8)));
typedef unsigned short ushort8v __attribute__((ext_vector_type(8)));
typedef float  f32x4  __attribute__((ext_vector_type(4)));

__device__ inline ushort_t f2bf(float f) {
    unsigned int u = __builtin_bit_cast(unsigned int, f);
    unsigned int r = u + 0x7fffu + ((u >> 16) & 1u);
    return (ushort_t)(r >> 16);
}
__device__ inline float bf2f(ushort_t u) {
    unsigned int x = ((unsigned int)u) << 16;
    return __builtin_bit_cast(float, x);
}

#define GL2L(g, l) __builtin_amdgcn_global_load_lds( \
    (const __attribute__((address_space(1))) void*)(g), \
    (__attribute__((address_space(3))) void*)(l), 16, 0, 0)

// ---------------- dequant: W[i] = bf16(T[i] * S[i/128]) ----------------
__global__ __launch_bounds__(256) void k_dequant(const int* __restrict__ T,
                                                 const float* __restrict__ S,
                                                 ushort_t* __restrict__ W) {
    int i = (blockIdx.x * 256 + threadIdx.x) * 4;
    int4 t = *(const int4*)(T + i);
    float s = S[i >> 7];
    ushort4 w;
    w.x = f2bf((float)t.x * s); w.y = f2bf((float)t.y * s);
    w.z = f2bf((float)t.z * s); w.w = f2bf((float)t.w * s);
    *(ushort4*)(W + i) = w;
}

// dequant with row interleave: source row r -> dest row 2r+which (for gate/up fuse)
__global__ __launch_bounds__(256) void k_dequant_il(const int* __restrict__ T,
                                                    const float* __restrict__ S,
                                                    ushort_t* __restrict__ W,
                                                    int which) {
    int i = (blockIdx.x * 256 + threadIdx.x) * 4;
    int4 t = *(const int4*)(T + i);
    float s = S[i >> 7];
    ushort4 w;
    w.x = f2bf((float)t.x * s); w.y = f2bf((float)t.y * s);
    w.z = f2bf((float)t.z * s); w.w = f2bf((float)t.w * s);
    int r = i >> 10, c = i & 1023;
    *(ushort4*)(W + (((size_t)((r << 1) | which)) << 10) + c) = w;
}

// ---------------- embedding: x[row,:] = t[id,:] * s[id, d/128] (fp32) ----------------
__global__ __launch_bounds__(256) void k_embed(const int* __restrict__ ids,
                                               const int* __restrict__ t,
                                               const float* __restrict__ s,
                                               float* __restrict__ x) {
    int row = blockIdx.x;
    int id  = ids[row];
    for (int d = threadIdx.x; d < DD; d += 256) {
        x[(size_t)row * DD + d] =
            (float)t[(size_t)id * DD + d] * s[id * (DD / GSZ) + (d >> 7)];
    }
}

// ---------------- rmsnorm: o = bf16(x * rsqrt(mean(x^2)+eps) * w) ----------------
__global__ __launch_bounds__(256) void k_rmsnorm(const float* __restrict__ x,
                                                 const float* __restrict__ w,
                                                 ushort_t* __restrict__ o) {
    int row = blockIdx.x;
    const float* xr = x + (size_t)row * DD;
    float ss = 0.f;
    for (int d = threadIdx.x; d < DD; d += 256) { float v = xr[d]; ss += v * v; }
    __shared__ float sm[4];
    for (int off = 32; off > 0; off >>= 1) ss += __shfl_down(ss, off, 64);
    if ((threadIdx.x & 63) == 0) sm[threadIdx.x >> 6] = ss;
    __syncthreads();
    float tot = sm[0] + sm[1] + sm[2] + sm[3];
    float inv = rsqrtf(tot / DD + EPS);
    for (int d = threadIdx.x; d < DD; d += 256)
        o[(size_t)row * DD + d] = f2bf(xr[d] * inv * w[d]);
}

// ---------------- bf16 MFMA GEMM: C[M,N] = A[M,K] @ W[N,K]^T ----------------
// m97 structure: 128x128 tile, BK=32, 256 thr = 4 waves, each wave 64x64 via
// 4x4 grid of mfma_f32_16x16x32_bf16. global_load_lds width=16 staging.
// 1-D grid, XCD-bijective chunking + y-fast-within-W-panel order (M/128 == 16
// always): 16 consecutive blocks on one XCD share a 256KB W panel -> W fetched
// ~once from HBM instead of 16x.
// MODE: 0 = store f32, 1 = add f32, 3 = store bf16,
//       4 = fused swiglu: W rows interleaved (even=gate, odd=up); even/odd
//           output cols pair via shfl_xor(1); write silu(g)*u bf16 at stride N/2.
template <int MODE>
__global__ __launch_bounds__(256) void gemm_bf16(const ushort_t* __restrict__ A,
                                                 const ushort_t* __restrict__ W,
                                                 float* __restrict__ Cf,
                                                 ushort_t* __restrict__ Cb,
                                                 int M, int N, int K) {
    __shared__ ushort_t As[128 * 32];
    __shared__ ushort_t Bs[128 * 32];
    const int tid  = threadIdx.x;
    const int wave = tid >> 6, lane = tid & 63;
    const int wm = wave >> 1, wn = wave & 1;

    const int nwg  = gridDim.x;
    const int orig = blockIdx.x;
    const int wgid = (orig & 7) * (nwg >> 3) + (orig >> 3);   // XCD-bijective
    const int i0 = (wgid & 15) * 128;                          // y-fast
    const int o0 = (wgid >> 4) * 128;

    f32x4 acc[4][4] = {};

    // staging: per wave, 2 calls for A + 2 for B; call covers 16 rows x 32 cols
    const int srow = wave * 32 + (lane >> 2);
    const int scol = (lane & 3) * 8;
    const ushort_t* aG0 = A + (size_t)(i0 + srow) * K + scol;
    const ushort_t* aG1 = aG0 + (size_t)16 * K;
    const ushort_t* bG0 = W + (size_t)(o0 + srow) * K + scol;
    const ushort_t* bG1 = bG0 + (size_t)16 * K;
    ushort_t* aL0 = As + wave * 1024;
    ushort_t* aL1 = aL0 + 512;
    ushort_t* bL0 = Bs + wave * 1024;
    ushort_t* bL1 = bL0 + 512;

    // fragment read base: A[m=lane&15][k=(lane>>4)*8 + j]
    const ushort_t* ap = As + (wm * 64 + (lane & 15)) * 32 + (lane >> 4) * 8;
    const ushort_t* bp = Bs + (wn * 64 + (lane & 15)) * 32 + (lane >> 4) * 8;

    for (int k0 = 0; k0 < K; k0 += 32) {
        __syncthreads();
        GL2L(aG0 + k0, aL0);
        GL2L(aG1 + k0, aL1);
        GL2L(bG0 + k0, bL0);
        GL2L(bG1 + k0, bL1);
        __syncthreads();
        bf16x8 av[4], bv[4];
#pragma unroll
        for (int t = 0; t < 4; ++t) {
            av[t] = __builtin_bit_cast(bf16x8, *(const short8*)(ap + t * 512));
            bv[t] = __builtin_bit_cast(bf16x8, *(const short8*)(bp + t * 512));
        }
#pragma unroll
        for (int mt = 0; mt < 4; ++mt)
#pragma unroll
            for (int nt = 0; nt < 4; ++nt)
                acc[mt][nt] = __builtin_amdgcn_mfma_f32_16x16x32_bf16(
                    av[mt], bv[nt], acc[mt][nt], 0, 0, 0);
    }

    // epilogue: C/D layout col=lane&15, row=(lane>>4)*4+reg
    const int r0 = wm * 64 + (lane >> 4) * 4;
    const int c0 = wn * 64 + (lane & 15);
#pragma unroll
    for (int mt = 0; mt < 4; ++mt) {
#pragma unroll
        for (int r = 0; r < 4; ++r) {
            const size_t row = i0 + r0 + mt * 16 + r;
#pragma unroll
            for (int nt = 0; nt < 4; ++nt) {
                const size_t col = o0 + c0 + nt * 16;
                const size_t idx = row * (size_t)N + col;
                float v = acc[mt][nt][r];
                if (MODE == 0) {
                    Cf[idx] = v;
                } else if (MODE == 1) {
                    Cf[idx] += v;
                } else if (MODE == 3) {
                    Cb[idx] = f2bf(v);
                } else {  // MODE 4: paired swiglu
                    float pv = __shfl_xor(v, 1, 64);
                    if (!(lane & 1)) {
                        float g = v, u = pv;
                        float res = g / (1.f + __expf(-g)) * u;
                        Cb[row * (size_t)(N >> 1) + (col >> 1)] = f2bf(res);
                    }
                }
            }
        }
    }
}

// ---------------- flash attention (MFMA): one block per (b,h,64-row q-tile) ----
__global__ __launch_bounds__(256) void k_fattn(const ushort_t* __restrict__ qkv,
                                               const ushort_t* __restrict__ hn,
                                               const float* __restrict__ alpha,
                                               ushort_t* __restrict__ out) {
    __shared__ ushort_t Ks[64][72];
    __shared__ ushort_t Vt[64][72];
    __shared__ ushort_t Ps[4][16][72];

    const int bid = blockIdx.x;
    const int bh  = bid & 31;           // b*16 + h
    const int qt  = 15 - (bid >> 5);    // heavy q-tiles dispatched first
    const int hh  = bh & 15;
    const int b   = bh >> 4;
    const int tid = threadIdx.x;
    const int wm  = tid >> 6;
    const int ln  = tid & 63;
    const int m16 = ln & 15;
    const int q4  = ln >> 4;

    const int bS0 = b * SS;
    const int q0  = qt * 64 + wm * 16;  // wave's first q row (local to batch b)

    // Q fragments: A[m=m16][k=(q4)*8+j], k-tiles 0 and 32
    bf16x8 qa0, qa1;
    {
        const ushort_t* qp = qkv + (size_t)(bS0 + q0 + m16) * 3072 + hh * DHH + q4 * 8;
        qa0 = __builtin_bit_cast(bf16x8, *(const ushort8v*)(qp));
        qa1 = __builtin_bit_cast(bf16x8, *(const ushort8v*)(qp + 32));
    }

    f32x4 oacc[4] = {};   // [dh-subtile]; row=q4*4+r, col=dh=dt*16+m16
    float mrow[4] = {-1e30f, -1e30f, -1e30f, -1e30f};
    float lrow[4] = {0.f, 0.f, 0.f, 0.f};

    const int c0a = tid, c1a = tid + 256;       // staging chunks
    const int r0a = c0a >> 3, cc0 = (c0a & 7) * 8;
    const int r1a = c1a >> 3, cc1 = (c1a & 7) * 8;

    for (int t = 0; t <= qt; ++t) {
        __syncthreads();
        {   // ---- stage K tile [64 keys][64 dh] row-major ----
            const size_t kbase = (size_t)(bS0 + t * 64) * 3072 + 1024 + hh * DHH;
            *(ushort8v*)&Ks[r0a][cc0] = *(const ushort8v*)(qkv + kbase + (size_t)r0a * 3072 + cc0);
            *(ushort8v*)&Ks[r1a][cc1] = *(const ushort8v*)(qkv + kbase + (size_t)r1a * 3072 + cc1);
            // ---- stage V tile transposed: Vt[dh][key] ----
            const size_t vbase = (size_t)(bS0 + t * 64) * 3072 + 2048 + hh * DHH;
            ushort8v v0 = *(const ushort8v*)(qkv + vbase + (size_t)r0a * 3072 + cc0);
#pragma unroll
            for (int j = 0; j < 8; ++j) Vt[cc0 + j][r0a] = v0[j];
            ushort8v v1 = *(const ushort8v*)(qkv + vbase + (size_t)r1a * 3072 + cc1);
#pragma unroll
            for (int j = 0; j < 8; ++j) Vt[cc1 + j][r1a] = v1[j];
        }
        __syncthreads();

        // ---- scores: S[16 q][64 key] in 4 C-frags ----
        f32x4 sc[4];
#pragma unroll
        for (int nt = 0; nt < 4; ++nt) {
            bf16x8 kb0 = __builtin_bit_cast(bf16x8, *(const ushort8v*)&Ks[nt * 16 + m16][q4 * 8]);
            bf16x8 kb1 = __builtin_bit_cast(bf16x8, *(const ushort8v*)&Ks[nt * 16 + m16][32 + q4 * 8]);
            f32x4 z = {};
            z = __builtin_amdgcn_mfma_f32_16x16x32_bf16(qa0, kb0, z, 0, 0, 0);
            sc[nt] = __builtin_amdgcn_mfma_f32_16x16x32_bf16(qa1, kb1, z, 0, 0, 0);
        }

        // ---- online softmax (per r: row = q4*4 + r across 16 lanes) ----
        const bool diag = (t == qt);
#pragma unroll
        for (int r = 0; r < 4; ++r) {
            float s0 = sc[0][r] * 0.125f;
            float s1 = sc[1][r] * 0.125f;
            float s2 = sc[2][r] * 0.125f;
            float s3 = sc[3][r] * 0.125f;
            if (diag) {
                const int rl = wm * 16 + q4 * 4 + r;   // row local to 64-block
                if (m16      > rl) s0 = -1e30f;
                if (m16 + 16 > rl) s1 = -1e30f;
                if (m16 + 32 > rl) s2 = -1e30f;
                if (m16 + 48 > rl) s3 = -1e30f;
            }
            float tm = fmaxf(fmaxf(s0, s1), fmaxf(s2, s3));
            tm = fmaxf(tm, __shfl_xor(tm, 1, 64));
            tm = fmaxf(tm, __shfl_xor(tm, 2, 64));
            tm = fmaxf(tm, __shfl_xor(tm, 4, 64));
            tm = fmaxf(tm, __shfl_xor(tm, 8, 64));
            const float mnew = fmaxf(mrow[r], tm);
            const float corr = __expf(mrow[r] - mnew);
            const float e0 = __expf(s0 - mnew);
            const float e1 = __expf(s1 - mnew);
            const float e2 = __expf(s2 - mnew);
            const float e3 = __expf(s3 - mnew);
            float rs = e0 + e1 + e2 + e3;
            rs += __shfl_xor(rs, 1, 64);
            rs += __shfl_xor(rs, 2, 64);
            rs += __shfl_xor(rs, 4, 64);
            rs += __shfl_xor(rs, 8, 64);
            lrow[r] = lrow[r] * corr + rs;
            mrow[r] = mnew;
#pragma unroll
            for (int dt = 0; dt < 4; ++dt) oacc[dt][r] *= corr;
            const int pr = q4 * 4 + r;
            Ps[wm][pr][m16]      = f2bf(e0);
            Ps[wm][pr][m16 + 16] = f2bf(e1);
            Ps[wm][pr][m16 + 32] = f2bf(e2);
            Ps[wm][pr][m16 + 48] = f2bf(e3);
        }

        // ---- O += P @ V : A = P[m=q][k=key], B = Vt[n=dh][k=key] ----
#pragma unroll
        for (int ks = 0; ks < 2; ++ks) {
            bf16x8 pa = __builtin_bit_cast(bf16x8, *(const ushort8v*)&Ps[wm][m16][ks * 32 + q4 * 8]);
#pragma unroll
            for (int dt = 0; dt < 4; ++dt) {
                bf16x8 vb = __builtin_bit_cast(bf16x8, *(const ushort8v*)&Vt[dt * 16 + m16][ks * 32 + q4 * 8]);
                oacc[dt] = __builtin_amdgcn_mfma_f32_16x16x32_bf16(pa, vb, oacc[dt], 0, 0, 0);
            }
        }
    }

    // ---- epilogue: out = o/l + alpha * hn ----
    const float al = alpha[hh];
#pragma unroll
    for (int r = 0; r < 4; ++r) {
        const float inv = 1.f / lrow[r];
        const size_t row = (size_t)(bS0 + q0 + q4 * 4 + r);
#pragma unroll
        for (int dt = 0; dt < 4; ++dt) {
            const size_t idx = row * DD + hh * DHH + dt * 16 + m16;
            out[idx] = f2bf(oacc[dt][r] * inv + al * bf2f(hn[idx]));
        }
    }
}

extern "C" void kernel_launch(void* const* d_in, const int* in_sizes, int n_in,
                              void* d_out, int out_size, void* d_ws, size_t ws_size,
                              hipStream_t stream) {
    const int*   ids   = (const int*)d_in[0];
    const int*   emb_t = (const int*)d_in[1];
    const float* emb_s = (const float*)d_in[2];
    const int*   qt    = (const int*)d_in[3];
    const float* qs    = (const float*)d_in[4];
    const int*   kt    = (const int*)d_in[5];
    const float* ks    = (const float*)d_in[6];
    const int*   vt    = (const int*)d_in[7];
    const float* vs    = (const float*)d_in[8];
    const int*   ot    = (const int*)d_in[9];
    const float* os    = (const float*)d_in[10];
    const int*   gatet = (const int*)d_in[11];
    const float* gates = (const float*)d_in[12];
    const int*   upt   = (const int*)d_in[13];
    const float* ups   = (const float*)d_in[14];
    const int*   downt = (const int*)d_in[15];
    const float* downs = (const float*)d_in[16];
    const float* wa    = (const float*)d_in[17];
    const float* wm    = (const float*)d_in[18];
    const float* alpha = (const float*)d_in[19];
    const float* wf    = (const float*)d_in[20];
    const int*   headt = (const int*)d_in[21];
    const float* heads = (const float*)d_in[22];

    // ---- workspace layout (byte offsets; region [0,75MB) is time-aliased) ----
    const size_t MB = 1ull << 20;
    char* wsb = (char*)d_ws;
    ushort_t* wbuf = (ushort_t*)(wsb);            // <= 65.6MB (head); 16.8MB (ffn)
    ushort_t* gb   = (ushort_t*)(wsb + 58 * MB);  // 16.8MB
    float*    x    = (float*)   (wsb + 75 * MB);  // 8.4MB
    ushort_t* h    = (ushort_t*)(wsb + 84 * MB);  // 4.2MB
    ushort_t* qkvb = (ushort_t*)(wsb + 89 * MB);  // 12.6MB  [BSR, 3072]
    ushort_t* ao   = (ushort_t*)(wsb + 102 * MB); // 4.2MB   ends ~106.2MB

    const size_t wDD = (size_t)DD * DD;       // 1M elems
    const size_t sDD = wDD / GSZ;
    const size_t wFD = (size_t)DFFD * DD;     // 4M elems
    const size_t sFD = wFD / GSZ;

    k_embed<<<BSR, 256, 0, stream>>>(ids, emb_t, emb_s, x);

    for (int l = 0; l < LL; ++l) {
        k_rmsnorm<<<BSR, 256, 0, stream>>>(x, wa + l * DD, h);
        // fused QKV weights -> wbuf [3072, 1024]
        k_dequant<<<wDD / 1024, 256, 0, stream>>>(qt + l * wDD, qs + l * sDD, wbuf);
        k_dequant<<<wDD / 1024, 256, 0, stream>>>(kt + l * wDD, ks + l * sDD, wbuf + wDD);
        k_dequant<<<wDD / 1024, 256, 0, stream>>>(vt + l * wDD, vs + l * sDD, wbuf + 2 * wDD);
        gemm_bf16<3><<<24 * 16, 256, 0, stream>>>(h, wbuf, nullptr, qkvb, BSR, 3072, DD);
        // flash attention: (S/64) q-tiles x B x H = 16 * 32 = 512 blocks
        k_fattn<<<16 * BB * HH, 256, 0, stream>>>(qkvb, h, alpha + l * HH, ao);
        k_dequant<<<wDD / 1024, 256, 0, stream>>>(ot + l * wDD, os + l * sDD, wbuf);
        gemm_bf16<1><<<8 * 16, 256, 0, stream>>>(ao, wbuf, x, nullptr, BSR, DD, DD);

        k_rmsnorm<<<BSR, 256, 0, stream>>>(x, wm + l * DD, h);
        // gate/up interleaved -> one N=8192 gemm with fused swiglu epilogue
        k_dequant_il<<<wFD / 1024, 256, 0, stream>>>(gatet + l * wFD, gates + l * sFD, wbuf, 0);
        k_dequant_il<<<wFD / 1024, 256, 0, stream>>>(upt + l * wFD, ups + l * sFD, wbuf, 1);
        gemm_bf16<4><<<64 * 16, 256, 0, stream>>>(h, wbuf, nullptr, gb, BSR, 8192, DD);
        k_dequant<<<wFD / 1024, 256, 0, stream>>>(downt + l * wFD, downs + l * sFD, wbuf);
        gemm_bf16<1><<<8 * 16, 256, 0, stream>>>(gb, wbuf, x, nullptr, BSR, DD, DFFD);
    }

    k_rmsnorm<<<BSR, 256, 0, stream>>>(x, wf, h);
    k_dequant<<<((size_t)VV * DD) / 1024, 256, 0, stream>>>(headt, heads, wbuf);
    gemm_bf16<0><<<250 * 16, 256, 0, stream>>>(h, wbuf, (float*)d_out, nullptr, BSR, VV, DD);
}

// Round 4
// 1185.225 us; speedup vs baseline: 1.8927x; 1.0267x over previous
//
#include <hip/hip_runtime.h>
#include <math.h>
#include <stdint.h>

// dims
#define BB   2
#define SS   1024
#define DD   1024
#define HH   16
#define DHH  64
#define DFFD 4096
#define LL   2
#define VV   32000
#define GSZ  128
#define BSR  (BB*SS)   // 2048 rows
constexpr float EPS = 1e-6f;

typedef unsigned short ushort_t;
typedef __bf16 bf16x8 __attribute__((ext_vector_type(8)));
typedef short  short8 __attribute__((ext_vector_type(8)));
typedef unsigned short ushort8v __attribute__((ext_vector_type(8)));
typedef float  f32x4  __attribute__((ext_vector_type(4)));

__device__ inline ushort_t f2bf(float f) {
    unsigned int u = __builtin_bit_cast(unsigned int, f);
    unsigned int r = u + 0x7fffu + ((u >> 16) & 1u);
    return (ushort_t)(r >> 16);
}
__device__ inline float bf2f(ushort_t u) {
    unsigned int x = ((unsigned int)u) << 16;
    return __builtin_bit_cast(float, x);
}

#define GL2L(g, l) __builtin_amdgcn_global_load_lds( \
    (const __attribute__((address_space(1))) void*)(g), \
    (__attribute__((address_space(3))) void*)(l), 16, 0, 0)

// ---------------- dequant: W[i] = bf16(T[i] * S[i/128]) ----------------
__global__ __launch_bounds__(256) void k_dequant(const int* __restrict__ T,
                                                 const float* __restrict__ S,
                                                 ushort_t* __restrict__ W) {
    int i = (blockIdx.x * 256 + threadIdx.x) * 4;
    int4 t = *(const int4*)(T + i);
    float s = S[i >> 7];
    ushort4 w;
    w.x = f2bf((float)t.x * s); w.y = f2bf((float)t.y * s);
    w.z = f2bf((float)t.z * s); w.w = f2bf((float)t.w * s);
    *(ushort4*)(W + i) = w;
}

// dequant with row interleave: source row r -> dest row 2r+which (for gate/up fuse)
__global__ __launch_bounds__(256) void k_dequant_il(const int* __restrict__ T,
                                                    const float* __restrict__ S,
                                                    ushort_t* __restrict__ W,
                                                    int which) {
    int i = (blockIdx.x * 256 + threadIdx.x) * 4;
    int4 t = *(const int4*)(T + i);
    float s = S[i >> 7];
    ushort4 w;
    w.x = f2bf((float)t.x * s); w.y = f2bf((float)t.y * s);
    w.z = f2bf((float)t.z * s); w.w = f2bf((float)t.w * s);
    int r = i >> 10, c = i & 1023;
    *(ushort4*)(W + (((size_t)((r << 1) | which)) << 10) + c) = w;
}

// ---------------- embedding ----------------
__global__ __launch_bounds__(256) void k_embed(const int* __restrict__ ids,
                                               const int* __restrict__ t,
                                               const float* __restrict__ s,
                                               float* __restrict__ x) {
    int row = blockIdx.x;
    int id  = ids[row];
    for (int d = threadIdx.x; d < DD; d += 256) {
        x[(size_t)row * DD + d] =
            (float)t[(size_t)id * DD + d] * s[id * (DD / GSZ) + (d >> 7)];
    }
}

// ---------------- rmsnorm ----------------
__global__ __launch_bounds__(256) void k_rmsnorm(const float* __restrict__ x,
                                                 const float* __restrict__ w,
                                                 ushort_t* __restrict__ o) {
    int row = blockIdx.x;
    const float* xr = x + (size_t)row * DD;
    float ss = 0.f;
    for (int d = threadIdx.x; d < DD; d += 256) { float v = xr[d]; ss += v * v; }
    __shared__ float sm[4];
    for (int off = 32; off > 0; off >>= 1) ss += __shfl_down(ss, off, 64);
    if ((threadIdx.x & 63) == 0) sm[threadIdx.x >> 6] = ss;
    __syncthreads();
    float tot = sm[0] + sm[1] + sm[2] + sm[3];
    float inv = rsqrtf(tot / DD + EPS);
    for (int d = threadIdx.x; d < DD; d += 256)
        o[(size_t)row * DD + d] = f2bf(xr[d] * inv * w[d]);
}

// ---------------- 128x128 bf16 MFMA GEMM (m97 structure) ----------------
// For the small-N gemms (qkv / o-proj / down) where 256^2 grids would be tiny.
// MODE: 1 = add f32, 3 = store bf16
template <int MODE>
__global__ __launch_bounds__(256) void gemm_bf16(const ushort_t* __restrict__ A,
                                                 const ushort_t* __restrict__ W,
                                                 float* __restrict__ Cf,
                                                 ushort_t* __restrict__ Cb,
                                                 int M, int N, int K) {
    __shared__ ushort_t As[128 * 32];
    __shared__ ushort_t Bs[128 * 32];
    const int tid  = threadIdx.x;
    const int wave = tid >> 6, lane = tid & 63;
    const int wm = wave >> 1, wn = wave & 1;

    const int nwg  = gridDim.x;
    const int orig = blockIdx.x;
    const int wgid = (orig & 7) * (nwg >> 3) + (orig >> 3);   // XCD-bijective
    const int i0 = (wgid & 15) * 128;                          // y-fast
    const int o0 = (wgid >> 4) * 128;

    f32x4 acc[4][4] = {};

    const int srow = wave * 32 + (lane >> 2);
    const int scol = (lane & 3) * 8;
    const ushort_t* aG0 = A + (size_t)(i0 + srow) * K + scol;
    const ushort_t* aG1 = aG0 + (size_t)16 * K;
    const ushort_t* bG0 = W + (size_t)(o0 + srow) * K + scol;
    const ushort_t* bG1 = bG0 + (size_t)16 * K;
    ushort_t* aL0 = As + wave * 1024;
    ushort_t* aL1 = aL0 + 512;
    ushort_t* bL0 = Bs + wave * 1024;
    ushort_t* bL1 = bL0 + 512;

    const ushort_t* ap = As + (wm * 64 + (lane & 15)) * 32 + (lane >> 4) * 8;
    const ushort_t* bp = Bs + (wn * 64 + (lane & 15)) * 32 + (lane >> 4) * 8;

    for (int k0 = 0; k0 < K; k0 += 32) {
        __syncthreads();
        GL2L(aG0 + k0, aL0);
        GL2L(aG1 + k0, aL1);
        GL2L(bG0 + k0, bL0);
        GL2L(bG1 + k0, bL1);
        __syncthreads();
        bf16x8 av[4], bv[4];
#pragma unroll
        for (int t = 0; t < 4; ++t) {
            av[t] = __builtin_bit_cast(bf16x8, *(const short8*)(ap + t * 512));
            bv[t] = __builtin_bit_cast(bf16x8, *(const short8*)(bp + t * 512));
        }
#pragma unroll
        for (int mt = 0; mt < 4; ++mt)
#pragma unroll
            for (int nt = 0; nt < 4; ++nt)
                acc[mt][nt] = __builtin_amdgcn_mfma_f32_16x16x32_bf16(
                    av[mt], bv[nt], acc[mt][nt], 0, 0, 0);
    }

    const int r0 = wm * 64 + (lane >> 4) * 4;
    const int c0 = wn * 64 + (lane & 15);
#pragma unroll
    for (int mt = 0; mt < 4; ++mt) {
#pragma unroll
        for (int r = 0; r < 4; ++r) {
            const size_t row = i0 + r0 + mt * 16 + r;
#pragma unroll
            for (int nt = 0; nt < 4; ++nt) {
                const size_t col = o0 + c0 + nt * 16;
                const size_t idx = row * (size_t)N + col;
                float v = acc[mt][nt][r];
                if (MODE == 1) Cf[idx] += v;
                else           Cb[idx] = f2bf(v);
            }
        }
    }
}

// ---------------- 256x256 8-phase bf16 MFMA GEMM (T2+T3+T4+T5) ----------------
// BM=BN=256, BK=64, 512 thr = 8 waves (2M x 4N), per-wave out 128x64.
// LDS 128 KiB: slots A0 A1 B0 B1 (each 256x64 bf16 = 32 KB), in-place recycled:
//   B(tile) dies after its first phase; A quarter dies per phase.
// Counted vmcnt(4) at phases 4/8 only (one K-tile = 4 gload calls stays in flight).
// Swizzle: element col ^= 32*(row&1) ^ 16*((row>>2)&1) ^ 8*((row>>3)&1),
// realized as pre-swizzled GLOBAL source (linear gload_lds dest) + same XOR on
// ds_read addresses -> floor-spread b128 fragment reads.
// M == 2048 fixed (M/256 == 8). MODE: 0 = store f32, 4 = fused swiglu bf16.
#define BAR()    __builtin_amdgcn_s_barrier()
#define WAITL0() do { asm volatile("s_waitcnt lgkmcnt(0)" ::: "memory"); \
                      __builtin_amdgcn_sched_barrier(0); } while (0)
#define WAITV4() asm volatile("s_waitcnt vmcnt(4)" ::: "memory")

#define STG(gbase, sbase, tile, half, call) do {                          \
    int _ko = (tile) * 64; if (_ko > K - 64) _ko = K - 64;                \
    GL2L((gbase) + (size_t)((half) * 128 + (call) * 64) * K + _ko,        \
         (sbase) + (half) * 8192 + (call) * 4096); } while (0)

#define RD_B(so) do { _Pragma("unroll") for (int nf = 0; nf < 4; ++nf) {  \
    bfr[nf][0] = __builtin_bit_cast(bf16x8, *(const short8*)(rB + (so) + nf * 1024 + colA0)); \
    bfr[nf][1] = __builtin_bit_cast(bf16x8, *(const short8*)(rB + (so) + nf * 1024 + colA1)); } } while (0)

#define RD_A(so, mf0) do { _Pragma("unroll") for (int i = 0; i < 2; ++i) { \
    afr[i][0] = __builtin_bit_cast(bf16x8, *(const short8*)(rA + (so) + ((mf0) + i) * 1024 + colA0)); \
    afr[i][1] = __builtin_bit_cast(bf16x8, *(const short8*)(rA + (so) + ((mf0) + i) * 1024 + colA1)); } } while (0)

#define MFMA16(mf0) do {                                                   \
    __builtin_amdgcn_s_setprio(1);                                         \
    _Pragma("unroll") for (int i = 0; i < 2; ++i)                          \
    _Pragma("unroll") for (int nf = 0; nf < 4; ++nf) {                     \
        acc[(mf0) + i][nf] = __builtin_amdgcn_mfma_f32_16x16x32_bf16(      \
            afr[i][0], bfr[nf][0], acc[(mf0) + i][nf], 0, 0, 0);           \
        acc[(mf0) + i][nf] = __builtin_amdgcn_mfma_f32_16x16x32_bf16(      \
            afr[i][1], bfr[nf][1], acc[(mf0) + i][nf], 0, 0, 0); }         \
    __builtin_amdgcn_s_setprio(0); } while (0)

template <int MODE>
__global__ __launch_bounds__(512, 2) void gemm256(const ushort_t* __restrict__ A,
                                                  const ushort_t* __restrict__ W,
                                                  float* __restrict__ Cf,
                                                  ushort_t* __restrict__ Cb,
                                                  int N, int K) {
    __shared__ ushort_t smem[65536];   // A0 | A1 | B0 | B1, 16384 ushorts each

    const int tid = threadIdx.x;
    const int w   = tid >> 6;
    const int l   = tid & 63;
    const int wm  = w >> 2;
    const int wn  = w & 3;
    const int m16 = l & 15;
    const int q4  = l >> 4;

    const int nwg  = gridDim.x;
    const int orig = blockIdx.x;
    const int wgid = (orig & 7) * (nwg >> 3) + (orig >> 3);   // XCD-bijective
    const int i0   = (wgid & 7) * 256;                         // y-fast (M=2048)
    const int o0   = (wgid >> 3) * 256;

    // staging: per call, wave w covers 8 rows x 64 cols (1 KiB); source col
    // pre-swizzled so a linear LDS write realizes the XOR layout.
    const int sc = ((l & 7) * 8) ^ ((l & 32) ? 16 : 0) ^ ((w & 1) ? 8 : 0)
                                 ^ ((l & 8) ? 32 : 0);
    const int srow = w * 8 + (l >> 3);
    const ushort_t* gA = A + (size_t)(i0 + srow) * K + sc;
    const ushort_t* gB = W + (size_t)(o0 + srow) * K + sc;
    ushort_t* sA0 = smem + w * 512;
    ushort_t* sA1 = sA0 + 16384;
    ushort_t* sB0 = sA0 + 32768;
    ushort_t* sB1 = sA0 + 49152;

    // fragment read bases (+ swizzled col)
    const int colA0 = (q4 * 8) ^ ((l & 1) << 5) ^ ((l & 4) << 2) ^ (l & 8);
    const int colA1 = colA0 ^ 32;
    const ushort_t* rA = smem + (wm * 128 + m16) * 64;
    const ushort_t* rB = smem + 32768 + (wn * 64 + m16) * 64;

    f32x4 acc[8][4] = {};
    bf16x8 bfr[4][2];
    bf16x8 afr[2][2];

    // prologue: B(0), A(0), B(1); wait until tile 0 (first 8 calls) landed
    STG(gB, sB0, 0, 0, 0); STG(gB, sB0, 0, 0, 1);
    STG(gB, sB0, 0, 1, 0); STG(gB, sB0, 0, 1, 1);
    STG(gA, sA0, 0, 0, 0); STG(gA, sA0, 0, 0, 1);
    STG(gA, sA0, 0, 1, 0); STG(gA, sA0, 0, 1, 1);
    STG(gB, sB1, 1, 0, 0); STG(gB, sB1, 1, 0, 1);
    STG(gB, sB1, 1, 1, 0); STG(gB, sB1, 1, 1, 1);
    WAITV4();
    BAR();

    const int niter = K >> 7;
    for (int it = 0; it < niter; ++it) {
        const int t0 = it * 2;
        // ph1: B(t0)+A(t0) q0 reads; issue A(t0+1) (consumed ph5, gated ph4)
        RD_B(0); RD_A(0, 0);
        STG(gA, sA1, t0 + 1, 0, 0); STG(gA, sA1, t0 + 1, 0, 1);
        STG(gA, sA1, t0 + 1, 1, 0); STG(gA, sA1, t0 + 1, 1, 1);
        BAR(); WAITL0(); MFMA16(0); BAR();
        // ph2: B0 region free -> B(t0+2) h0
        RD_A(0, 2);
        STG(gB, sB0, t0 + 2, 0, 0); STG(gB, sB0, t0 + 2, 0, 1);
        BAR(); WAITL0(); MFMA16(2); BAR();
        // ph3: B(t0+2) h1
        RD_A(0, 4);
        STG(gB, sB0, t0 + 2, 1, 0); STG(gB, sB0, t0 + 2, 1, 1);
        BAR(); WAITL0(); MFMA16(4); BAR();
        // ph4: gate tile t0+1 (B1 from prev ph7/8 + A1 from ph1)
        RD_A(0, 6);
        BAR(); WAITL0(); MFMA16(6);
        WAITV4(); BAR();
        // ph5: compute tile t0+1; A0 free -> A(t0+2) h0
        RD_B(16384); RD_A(16384, 0);
        STG(gA, sA0, t0 + 2, 0, 0); STG(gA, sA0, t0 + 2, 0, 1);
        BAR(); WAITL0(); MFMA16(0); BAR();
        // ph6: A(t0+2) h1
        RD_A(16384, 2);
        STG(gA, sA0, t0 + 2, 1, 0); STG(gA, sA0, t0 + 2, 1, 1);
        BAR(); WAITL0(); MFMA16(2); BAR();
        // ph7: B1 free -> B(t0+3) h0
        RD_A(16384, 4);
        STG(gB, sB1, t0 + 3, 0, 0); STG(gB, sB1, t0 + 3, 0, 1);
        BAR(); WAITL0(); MFMA16(4); BAR();
        // ph8: B(t0+3) h1; gate tile t0+2
        RD_A(16384, 6);
        STG(gB, sB1, t0 + 3, 1, 0); STG(gB, sB1, t0 + 3, 1, 1);
        BAR(); WAITL0(); MFMA16(6);
        WAITV4(); BAR();
    }

    // drain all pending LDS-DMA before epilogue / wave exit (safety)
    asm volatile("s_waitcnt vmcnt(0) lgkmcnt(0)" ::: "memory");
    BAR();

    // epilogue: C/D layout col=lane&15, row=(lane>>4)*4+reg
    const int r0 = i0 + wm * 128 + q4 * 4;
    const int c0 = o0 + wn * 64 + m16;
#pragma unroll
    for (int mf = 0; mf < 8; ++mf) {
#pragma unroll
        for (int rr = 0; rr < 4; ++rr) {
            const size_t row = r0 + mf * 16 + rr;
#pragma unroll
            for (int nf = 0; nf < 4; ++nf) {
                const size_t col = c0 + nf * 16;
                float v = acc[mf][nf][rr];
                if (MODE == 0) {
                    Cf[row * (size_t)N + col] = v;
                } else {  // MODE 4: paired swiglu (even col = gate, odd = up)
                    float pv = __shfl_xor(v, 1, 64);
                    if (!(l & 1)) {
                        float res = v / (1.f + __expf(-v)) * pv;
                        Cb[row * (size_t)(N >> 1) + (col >> 1)] = f2bf(res);
                    }
                }
            }
        }
    }
}

// ---------------- flash attention (MFMA): one block per (b,h,64-row q-tile) ----
__global__ __launch_bounds__(256) void k_fattn(const ushort_t* __restrict__ qkv,
                                               const ushort_t* __restrict__ hn,
                                               const float* __restrict__ alpha,
                                               ushort_t* __restrict__ out) {
    __shared__ ushort_t Ks[64][72];
    __shared__ ushort_t Vt[64][72];
    __shared__ ushort_t Ps[4][16][72];

    const int bid = blockIdx.x;
    const int bh  = bid & 31;           // b*16 + h
    const int qt  = 15 - (bid >> 5);    // heavy q-tiles dispatched first
    const int hh  = bh & 15;
    const int b   = bh >> 4;
    const int tid = threadIdx.x;
    const int wm  = tid >> 6;
    const int ln  = tid & 63;
    const int m16 = ln & 15;
    const int q4  = ln >> 4;

    const int bS0 = b * SS;
    const int q0  = qt * 64 + wm * 16;

    bf16x8 qa0, qa1;
    {
        const ushort_t* qp = qkv + (size_t)(bS0 + q0 + m16) * 3072 + hh * DHH + q4 * 8;
        qa0 = __builtin_bit_cast(bf16x8, *(const ushort8v*)(qp));
        qa1 = __builtin_bit_cast(bf16x8, *(const ushort8v*)(qp + 32));
    }

    f32x4 oacc[4] = {};
    float mrow[4] = {-1e30f, -1e30f, -1e30f, -1e30f};
    float lrow[4] = {0.f, 0.f, 0.f, 0.f};

    const int c0a = tid, c1a = tid + 256;
    const int r0a = c0a >> 3, cc0 = (c0a & 7) * 8;
    const int r1a = c1a >> 3, cc1 = (c1a & 7) * 8;

    for (int t = 0; t <= qt; ++t) {
        __syncthreads();
        {
            const size_t kbase = (size_t)(bS0 + t * 64) * 3072 + 1024 + hh * DHH;
            *(ushort8v*)&Ks[r0a][cc0] = *(const ushort8v*)(qkv + kbase + (size_t)r0a * 3072 + cc0);
            *(ushort8v*)&Ks[r1a][cc1] = *(const ushort8v*)(qkv + kbase + (size_t)r1a * 3072 + cc1);
            const size_t vbase = (size_t)(bS0 + t * 64) * 3072 + 2048 + hh * DHH;
            ushort8v v0 = *(const ushort8v*)(qkv + vbase + (size_t)r0a * 3072 + cc0);
#pragma unroll
            for (int j = 0; j < 8; ++j) Vt[cc0 + j][r0a] = v0[j];
            ushort8v v1 = *(const ushort8v*)(qkv + vbase + (size_t)r1a * 3072 + cc1);
#pragma unroll
            for (int j = 0; j < 8; ++j) Vt[cc1 + j][r1a] = v1[j];
        }
        __syncthreads();

        f32x4 sc[4];
#pragma unroll
        for (int nt = 0; nt < 4; ++nt) {
            bf16x8 kb0 = __builtin_bit_cast(bf16x8, *(const ushort8v*)&Ks[nt * 16 + m16][q4 * 8]);
            bf16x8 kb1 = __builtin_bit_cast(bf16x8, *(const ushort8v*)&Ks[nt * 16 + m16][32 + q4 * 8]);
            f32x4 z = {};
            z = __builtin_amdgcn_mfma_f32_16x16x32_bf16(qa0, kb0, z, 0, 0, 0);
            sc[nt] = __builtin_amdgcn_mfma_f32_16x16x32_bf16(qa1, kb1, z, 0, 0, 0);
        }

        const bool diag = (t == qt);
#pragma unroll
        for (int r = 0; r < 4; ++r) {
            float s0 = sc[0][r] * 0.125f;
            float s1 = sc[1][r] * 0.125f;
            float s2 = sc[2][r] * 0.125f;
            float s3 = sc[3][r] * 0.125f;
            if (diag) {
                const int rl = wm * 16 + q4 * 4 + r;
                if (m16      > rl) s0 = -1e30f;
                if (m16 + 16 > rl) s1 = -1e30f;
                if (m16 + 32 > rl) s2 = -1e30f;
                if (m16 + 48 > rl) s3 = -1e30f;
            }
            float tm = fmaxf(fmaxf(s0, s1), fmaxf(s2, s3));
            tm = fmaxf(tm, __shfl_xor(tm, 1, 64));
            tm = fmaxf(tm, __shfl_xor(tm, 2, 64));
            tm = fmaxf(tm, __shfl_xor(tm, 4, 64));
            tm = fmaxf(tm, __shfl_xor(tm, 8, 64));
            const float mnew = fmaxf(mrow[r], tm);
            const float corr = __expf(mrow[r] - mnew);
            const float e0 = __expf(s0 - mnew);
            const float e1 = __expf(s1 - mnew);
            const float e2 = __expf(s2 - mnew);
            const float e3 = __expf(s3 - mnew);
            float rs = e0 + e1 + e2 + e3;
            rs += __shfl_xor(rs, 1, 64);
            rs += __shfl_xor(rs, 2, 64);
            rs += __shfl_xor(rs, 4, 64);
            rs += __shfl_xor(rs, 8, 64);
            lrow[r] = lrow[r] * corr + rs;
            mrow[r] = mnew;
#pragma unroll
            for (int dt = 0; dt < 4; ++dt) oacc[dt][r] *= corr;
            const int pr = q4 * 4 + r;
            Ps[wm][pr][m16]      = f2bf(e0);
            Ps[wm][pr][m16 + 16] = f2bf(e1);
            Ps[wm][pr][m16 + 32] = f2bf(e2);
            Ps[wm][pr][m16 + 48] = f2bf(e3);
        }

#pragma unroll
        for (int ks = 0; ks < 2; ++ks) {
            bf16x8 pa = __builtin_bit_cast(bf16x8, *(const ushort8v*)&Ps[wm][m16][ks * 32 + q4 * 8]);
#pragma unroll
            for (int dt = 0; dt < 4; ++dt) {
                bf16x8 vb = __builtin_bit_cast(bf16x8, *(const ushort8v*)&Vt[dt * 16 + m16][ks * 32 + q4 * 8]);
                oacc[dt] = __builtin_amdgcn_mfma_f32_16x16x32_bf16(pa, vb, oacc[dt], 0, 0, 0);
            }
        }
    }

    const float al = alpha[hh];
#pragma unroll
    for (int r = 0; r < 4; ++r) {
        const float inv = 1.f / lrow[r];
        const size_t row = (size_t)(bS0 + q0 + q4 * 4 + r);
#pragma unroll
        for (int dt = 0; dt < 4; ++dt) {
            const size_t idx = row * DD + hh * DHH + dt * 16 + m16;
            out[idx] = f2bf(oacc[dt][r] * inv + al * bf2f(hn[idx]));
        }
    }
}

extern "C" void kernel_launch(void* const* d_in, const int* in_sizes, int n_in,
                              void* d_out, int out_size, void* d_ws, size_t ws_size,
                              hipStream_t stream) {
    const int*   ids   = (const int*)d_in[0];
    const int*   emb_t = (const int*)d_in[1];
    const float* emb_s = (const float*)d_in[2];
    const int*   qt    = (const int*)d_in[3];
    const float* qs    = (const float*)d_in[4];
    const int*   kt    = (const int*)d_in[5];
    const float* ks    = (const float*)d_in[6];
    const int*   vt    = (const int*)d_in[7];
    const float* vs    = (const float*)d_in[8];
    const int*   ot    = (const int*)d_in[9];
    const float* os    = (const float*)d_in[10];
    const int*   gatet = (const int*)d_in[11];
    const float* gates = (const float*)d_in[12];
    const int*   upt   = (const int*)d_in[13];
    const float* ups   = (const float*)d_in[14];
    const int*   downt = (const int*)d_in[15];
    const float* downs = (const float*)d_in[16];
    const float* wa    = (const float*)d_in[17];
    const float* wm    = (const float*)d_in[18];
    const float* alpha = (const float*)d_in[19];
    const float* wf    = (const float*)d_in[20];
    const int*   headt = (const int*)d_in[21];
    const float* heads = (const float*)d_in[22];

    // ---- workspace layout (byte offsets; region [0,75MB) is time-aliased) ----
    const size_t MB = 1ull << 20;
    char* wsb = (char*)d_ws;
    ushort_t* wbuf = (ushort_t*)(wsb);            // <= 65.6MB (head); 16.8MB (ffn)
    ushort_t* gb   = (ushort_t*)(wsb + 58 * MB);  // 16.8MB
    float*    x    = (float*)   (wsb + 75 * MB);  // 8.4MB
    ushort_t* h    = (ushort_t*)(wsb + 84 * MB);  // 4.2MB
    ushort_t* qkvb = (ushort_t*)(wsb + 89 * MB);  // 12.6MB  [BSR, 3072]
    ushort_t* ao   = (ushort_t*)(wsb + 102 * MB); // 4.2MB   ends ~106.2MB

    const size_t wDD = (size_t)DD * DD;
    const size_t sDD = wDD / GSZ;
    const size_t wFD = (size_t)DFFD * DD;
    const size_t sFD = wFD / GSZ;

    k_embed<<<BSR, 256, 0, stream>>>(ids, emb_t, emb_s, x);

    for (int l = 0; l < LL; ++l) {
        k_rmsnorm<<<BSR, 256, 0, stream>>>(x, wa + l * DD, h);
        k_dequant<<<wDD / 1024, 256, 0, stream>>>(qt + l * wDD, qs + l * sDD, wbuf);
        k_dequant<<<wDD / 1024, 256, 0, stream>>>(kt + l * wDD, ks + l * sDD, wbuf + wDD);
        k_dequant<<<wDD / 1024, 256, 0, stream>>>(vt + l * wDD, vs + l * sDD, wbuf + 2 * wDD);
        gemm_bf16<3><<<24 * 16, 256, 0, stream>>>(h, wbuf, nullptr, qkvb, BSR, 3072, DD);
        k_fattn<<<16 * BB * HH, 256, 0, stream>>>(qkvb, h, alpha + l * HH, ao);
        k_dequant<<<wDD / 1024, 256, 0, stream>>>(ot + l * wDD, os + l * sDD, wbuf);
        gemm_bf16<1><<<8 * 16, 256, 0, stream>>>(ao, wbuf, x, nullptr, BSR, DD, DD);

        k_rmsnorm<<<BSR, 256, 0, stream>>>(x, wm + l * DD, h);
        k_dequant_il<<<wFD / 1024, 256, 0, stream>>>(gatet + l * wFD, gates + l * sFD, wbuf, 0);
        k_dequant_il<<<wFD / 1024, 256, 0, stream>>>(upt + l * wFD, ups + l * sFD, wbuf, 1);
        gemm256<4><<<32 * 8, 512, 0, stream>>>(h, wbuf, nullptr, gb, 8192, DD);
        k_dequant<<<wFD / 1024, 256, 0, stream>>>(downt + l * wFD, downs + l * sFD, wbuf);
        gemm_bf16<1><<<8 * 16, 256, 0, stream>>>(gb, wbuf, x, nullptr, BSR, DD, DFFD);
    }

    k_rmsnorm<<<BSR, 256, 0, stream>>>(x, wf, h);
    k_dequant<<<((size_t)VV * DD) / 1024, 256, 0, stream>>>(headt, heads, wbuf);
    gemm256<0><<<125 * 8, 512, 0, stream>>>(h, wbuf, (float*)d_out, nullptr, VV, DD);
}

// Round 5
// 1136.346 us; speedup vs baseline: 1.9741x; 1.0430x over previous
//
#include <hip/hip_runtime.h>
#include <math.h>
#include <stdint.h>

// dims
#define BB   2
#define SS   1024
#define DD   1024
#define HH   16
#define DHH  64
#define DFFD 4096
#define LL   2
#define VV   32000
#define GSZ  128
#define BSR  (BB*SS)   // 2048 rows
constexpr float EPS = 1e-6f;

typedef unsigned short ushort_t;
typedef __bf16 bf16x8 __attribute__((ext_vector_type(8)));
typedef short  short8 __attribute__((ext_vector_type(8)));
typedef unsigned short ushort8v __attribute__((ext_vector_type(8)));
typedef float  f32x4  __attribute__((ext_vector_type(4)));

__device__ inline ushort_t f2bf(float f) {
    unsigned int u = __builtin_bit_cast(unsigned int, f);
    unsigned int r = u + 0x7fffu + ((u >> 16) & 1u);
    return (ushort_t)(r >> 16);
}
__device__ inline float bf2f(ushort_t u) {
    unsigned int x = ((unsigned int)u) << 16;
    return __builtin_bit_cast(float, x);
}

#define GL2L(g, l) __builtin_amdgcn_global_load_lds( \
    (const __attribute__((address_space(1))) void*)(g), \
    (__attribute__((address_space(3))) void*)(l), 16, 0, 0)

// ---------------- dequant: W[i] = bf16(T[i] * S[i/128]) ----------------
__global__ __launch_bounds__(256) void k_dequant(const int* __restrict__ T,
                                                 const float* __restrict__ S,
                                                 ushort_t* __restrict__ W) {
    int i = (blockIdx.x * 256 + threadIdx.x) * 4;
    int4 t = *(const int4*)(T + i);
    float s = S[i >> 7];
    ushort4 w;
    w.x = f2bf((float)t.x * s); w.y = f2bf((float)t.y * s);
    w.z = f2bf((float)t.z * s); w.w = f2bf((float)t.w * s);
    *(ushort4*)(W + i) = w;
}

// dequant with row interleave: source row r -> dest row 2r+which (for gate/up fuse)
__global__ __launch_bounds__(256) void k_dequant_il(const int* __restrict__ T,
                                                    const float* __restrict__ S,
                                                    ushort_t* __restrict__ W,
                                                    int which) {
    int i = (blockIdx.x * 256 + threadIdx.x) * 4;
    int4 t = *(const int4*)(T + i);
    float s = S[i >> 7];
    ushort4 w;
    w.x = f2bf((float)t.x * s); w.y = f2bf((float)t.y * s);
    w.z = f2bf((float)t.z * s); w.w = f2bf((float)t.w * s);
    int r = i >> 10, c = i & 1023;
    *(ushort4*)(W + (((size_t)((r << 1) | which)) << 10) + c) = w;
}

// ---------------- embedding ----------------
__global__ __launch_bounds__(256) void k_embed(const int* __restrict__ ids,
                                               const int* __restrict__ t,
                                               const float* __restrict__ s,
                                               float* __restrict__ x) {
    int row = blockIdx.x;
    int id  = ids[row];
    for (int d = threadIdx.x; d < DD; d += 256) {
        x[(size_t)row * DD + d] =
            (float)t[(size_t)id * DD + d] * s[id * (DD / GSZ) + (d >> 7)];
    }
}

// ---------------- rmsnorm ----------------
__global__ __launch_bounds__(256) void k_rmsnorm(const float* __restrict__ x,
                                                 const float* __restrict__ w,
                                                 ushort_t* __restrict__ o) {
    int row = blockIdx.x;
    const float* xr = x + (size_t)row * DD;
    float ss = 0.f;
    for (int d = threadIdx.x; d < DD; d += 256) { float v = xr[d]; ss += v * v; }
    __shared__ float sm[4];
    for (int off = 32; off > 0; off >>= 1) ss += __shfl_down(ss, off, 64);
    if ((threadIdx.x & 63) == 0) sm[threadIdx.x >> 6] = ss;
    __syncthreads();
    float tot = sm[0] + sm[1] + sm[2] + sm[3];
    float inv = rsqrtf(tot / DD + EPS);
    for (int d = threadIdx.x; d < DD; d += 256)
        o[(size_t)row * DD + d] = f2bf(xr[d] * inv * w[d]);
}

// ---------------- 128x128 bf16 MFMA GEMM (m97 structure) ----------------
// For the small-N gemms (qkv / o-proj / down) where 256^2 grids would be tiny.
// MODE: 1 = add f32, 3 = store bf16
template <int MODE>
__global__ __launch_bounds__(256) void gemm_bf16(const ushort_t* __restrict__ A,
                                                 const ushort_t* __restrict__ W,
                                                 float* __restrict__ Cf,
                                                 ushort_t* __restrict__ Cb,
                                                 int M, int N, int K) {
    __shared__ ushort_t As[128 * 32];
    __shared__ ushort_t Bs[128 * 32];
    const int tid  = threadIdx.x;
    const int wave = tid >> 6, lane = tid & 63;
    const int wm = wave >> 1, wn = wave & 1;

    const int nwg  = gridDim.x;
    const int orig = blockIdx.x;
    const int wgid = (orig & 7) * (nwg >> 3) + (orig >> 3);   // XCD-bijective
    const int i0 = (wgid & 15) * 128;                          // y-fast
    const int o0 = (wgid >> 4) * 128;

    f32x4 acc[4][4] = {};

    const int srow = wave * 32 + (lane >> 2);
    const int scol = (lane & 3) * 8;
    const ushort_t* aG0 = A + (size_t)(i0 + srow) * K + scol;
    const ushort_t* aG1 = aG0 + (size_t)16 * K;
    const ushort_t* bG0 = W + (size_t)(o0 + srow) * K + scol;
    const ushort_t* bG1 = bG0 + (size_t)16 * K;
    ushort_t* aL0 = As + wave * 1024;
    ushort_t* aL1 = aL0 + 512;
    ushort_t* bL0 = Bs + wave * 1024;
    ushort_t* bL1 = bL0 + 512;

    const ushort_t* ap = As + (wm * 64 + (lane & 15)) * 32 + (lane >> 4) * 8;
    const ushort_t* bp = Bs + (wn * 64 + (lane & 15)) * 32 + (lane >> 4) * 8;

    for (int k0 = 0; k0 < K; k0 += 32) {
        __syncthreads();
        GL2L(aG0 + k0, aL0);
        GL2L(aG1 + k0, aL1);
        GL2L(bG0 + k0, bL0);
        GL2L(bG1 + k0, bL1);
        __syncthreads();
        bf16x8 av[4], bv[4];
#pragma unroll
        for (int t = 0; t < 4; ++t) {
            av[t] = __builtin_bit_cast(bf16x8, *(const short8*)(ap + t * 512));
            bv[t] = __builtin_bit_cast(bf16x8, *(const short8*)(bp + t * 512));
        }
#pragma unroll
        for (int mt = 0; mt < 4; ++mt)
#pragma unroll
            for (int nt = 0; nt < 4; ++nt)
                acc[mt][nt] = __builtin_amdgcn_mfma_f32_16x16x32_bf16(
                    av[mt], bv[nt], acc[mt][nt], 0, 0, 0);
    }

    const int r0 = wm * 64 + (lane >> 4) * 4;
    const int c0 = wn * 64 + (lane & 15);
#pragma unroll
    for (int mt = 0; mt < 4; ++mt) {
#pragma unroll
        for (int r = 0; r < 4; ++r) {
            const size_t row = i0 + r0 + mt * 16 + r;
#pragma unroll
            for (int nt = 0; nt < 4; ++nt) {
                const size_t col = o0 + c0 + nt * 16;
                const size_t idx = row * (size_t)N + col;
                float v = acc[mt][nt][r];
                if (MODE == 1) Cf[idx] += v;
                else           Cb[idx] = f2bf(v);
            }
        }
    }
}

// ---------------- 256x256 8-phase bf16 MFMA GEMM (T2+T3+T4+T5) ----------------
// BM=BN=256, BK=64, 512 thr = 8 waves (2M x 4N), per-wave out 128x64.
// LDS 128 KiB: slots A0 A1 B0 B1 (each 256x64 bf16 = 32 KB), in-place recycled:
//   B(tile) dies after its first phase; A quarter dies per phase.
// Counted vmcnt(4) at phases 4/8 only (one K-tile = 4 gload calls stays in flight).
// Swizzle (bank-bijective): logical col c of row r stored at physical
//   c ^ 8*(r&7)  -> bank slot = q4 ^ (r&7), bijective on any 8 consecutive
// rows => conflict-free b128 fragment reads. Realized as pre-swizzled GLOBAL
// source (linear gload_lds dest) + same XOR on ds_read addresses.
// M == 2048 fixed (M/256 == 8). MODE: 0 = store f32, 4 = fused swiglu bf16.
#define BAR()    __builtin_amdgcn_s_barrier()
#define WAITL0() do { asm volatile("s_waitcnt lgkmcnt(0)" ::: "memory"); \
                      __builtin_amdgcn_sched_barrier(0); } while (0)
#define WAITV4() asm volatile("s_waitcnt vmcnt(4)" ::: "memory")

#define STG(gbase, sbase, tile, half, call) do {                          \
    int _ko = (tile) * 64; if (_ko > K - 64) _ko = K - 64;                \
    GL2L((gbase) + (size_t)((half) * 128 + (call) * 64) * K + _ko,        \
         (sbase) + (half) * 8192 + (call) * 4096); } while (0)

#define RD_B(so) do { _Pragma("unroll") for (int nf = 0; nf < 4; ++nf) {  \
    bfr[nf][0] = __builtin_bit_cast(bf16x8, *(const short8*)(rB + (so) + nf * 1024 + colA0)); \
    bfr[nf][1] = __builtin_bit_cast(bf16x8, *(const short8*)(rB + (so) + nf * 1024 + colA1)); } } while (0)

#define RD_A(so, mf0) do { _Pragma("unroll") for (int i = 0; i < 2; ++i) { \
    afr[i][0] = __builtin_bit_cast(bf16x8, *(const short8*)(rA + (so) + ((mf0) + i) * 1024 + colA0)); \
    afr[i][1] = __builtin_bit_cast(bf16x8, *(const short8*)(rA + (so) + ((mf0) + i) * 1024 + colA1)); } } while (0)

#define MFMA16(mf0) do {                                                   \
    __builtin_amdgcn_s_setprio(1);                                         \
    _Pragma("unroll") for (int i = 0; i < 2; ++i)                          \
    _Pragma("unroll") for (int nf = 0; nf < 4; ++nf) {                     \
        acc[(mf0) + i][nf] = __builtin_amdgcn_mfma_f32_16x16x32_bf16(      \
            afr[i][0], bfr[nf][0], acc[(mf0) + i][nf], 0, 0, 0);           \
        acc[(mf0) + i][nf] = __builtin_amdgcn_mfma_f32_16x16x32_bf16(      \
            afr[i][1], bfr[nf][1], acc[(mf0) + i][nf], 0, 0, 0); }         \
    __builtin_amdgcn_s_setprio(0); } while (0)

template <int MODE>
__global__ __launch_bounds__(512, 2) void gemm256(const ushort_t* __restrict__ A,
                                                  const ushort_t* __restrict__ W,
                                                  float* __restrict__ Cf,
                                                  ushort_t* __restrict__ Cb,
                                                  int N, int K) {
    __shared__ ushort_t smem[65536];   // A0 | A1 | B0 | B1, 16384 ushorts each

    const int tid = threadIdx.x;
    const int w   = tid >> 6;
    const int l   = tid & 63;
    const int wm  = w >> 2;
    const int wn  = w & 3;
    const int m16 = l & 15;
    const int q4  = l >> 4;

    const int nwg  = gridDim.x;
    const int orig = blockIdx.x;
    const int wgid = (orig & 7) * (nwg >> 3) + (orig >> 3);   // XCD-bijective
    const int i0   = (wgid & 7) * 256;                         // y-fast (M=2048)
    const int o0   = (wgid >> 3) * 256;

    // staging: per call, wave w covers 8 rows x 64 cols (1 KiB); source col
    // pre-swizzled so a linear LDS write realizes the XOR layout.
    // row-within-8 = l>>3, physical col of lane = (l&7)*8 -> needed logical
    // col = ((l&7)*8) ^ 8*(l>>3).
    const int sc = (((l & 7) ^ (l >> 3)) * 8);
    const int srow = w * 8 + (l >> 3);
    const ushort_t* gA = A + (size_t)(i0 + srow) * K + sc;
    const ushort_t* gB = W + (size_t)(o0 + srow) * K + sc;
    ushort_t* sA0 = smem + w * 512;
    ushort_t* sA1 = sA0 + 16384;
    ushort_t* sB0 = sA0 + 32768;
    ushort_t* sB1 = sA0 + 49152;

    // fragment read bases (+ swizzled col): physical = logical ^ 8*(row&7)
    const int colA0 = ((q4 ^ (m16 & 7)) * 8);
    const int colA1 = colA0 ^ 32;
    const ushort_t* rA = smem + (wm * 128 + m16) * 64;
    const ushort_t* rB = smem + 32768 + (wn * 64 + m16) * 64;

    f32x4 acc[8][4] = {};
    bf16x8 bfr[4][2];
    bf16x8 afr[2][2];

    // prologue: B(0), A(0), B(1); wait until tile 0 (first 8 calls) landed
    STG(gB, sB0, 0, 0, 0); STG(gB, sB0, 0, 0, 1);
    STG(gB, sB0, 0, 1, 0); STG(gB, sB0, 0, 1, 1);
    STG(gA, sA0, 0, 0, 0); STG(gA, sA0, 0, 0, 1);
    STG(gA, sA0, 0, 1, 0); STG(gA, sA0, 0, 1, 1);
    STG(gB, sB1, 1, 0, 0); STG(gB, sB1, 1, 0, 1);
    STG(gB, sB1, 1, 1, 0); STG(gB, sB1, 1, 1, 1);
    WAITV4();
    BAR();

    const int niter = K >> 7;
    for (int it = 0; it < niter; ++it) {
        const int t0 = it * 2;
        // ph1: B(t0)+A(t0) q0 reads; issue A(t0+1) (consumed ph5, gated ph4)
        RD_B(0); RD_A(0, 0);
        STG(gA, sA1, t0 + 1, 0, 0); STG(gA, sA1, t0 + 1, 0, 1);
        STG(gA, sA1, t0 + 1, 1, 0); STG(gA, sA1, t0 + 1, 1, 1);
        BAR(); WAITL0(); MFMA16(0); BAR();
        // ph2: B0 region free -> B(t0+2) h0
        RD_A(0, 2);
        STG(gB, sB0, t0 + 2, 0, 0); STG(gB, sB0, t0 + 2, 0, 1);
        BAR(); WAITL0(); MFMA16(2); BAR();
        // ph3: B(t0+2) h1
        RD_A(0, 4);
        STG(gB, sB0, t0 + 2, 1, 0); STG(gB, sB0, t0 + 2, 1, 1);
        BAR(); WAITL0(); MFMA16(4); BAR();
        // ph4: gate tile t0+1 (B1 from prev ph7/8 + A1 from ph1)
        RD_A(0, 6);
        BAR(); WAITL0(); MFMA16(6);
        WAITV4(); BAR();
        // ph5: compute tile t0+1; A0 free -> A(t0+2) h0
        RD_B(16384); RD_A(16384, 0);
        STG(gA, sA0, t0 + 2, 0, 0); STG(gA, sA0, t0 + 2, 0, 1);
        BAR(); WAITL0(); MFMA16(0); BAR();
        // ph6: A(t0+2) h1
        RD_A(16384, 2);
        STG(gA, sA0, t0 + 2, 1, 0); STG(gA, sA0, t0 + 2, 1, 1);
        BAR(); WAITL0(); MFMA16(2); BAR();
        // ph7: B1 free -> B(t0+3) h0
        RD_A(16384, 4);
        STG(gB, sB1, t0 + 3, 0, 0); STG(gB, sB1, t0 + 3, 0, 1);
        BAR(); WAITL0(); MFMA16(4); BAR();
        // ph8: B(t0+3) h1; gate tile t0+2
        RD_A(16384, 6);
        STG(gB, sB1, t0 + 3, 1, 0); STG(gB, sB1, t0 + 3, 1, 1);
        BAR(); WAITL0(); MFMA16(6);
        WAITV4(); BAR();
    }

    // drain all pending LDS-DMA before epilogue / wave exit (safety)
    asm volatile("s_waitcnt vmcnt(0) lgkmcnt(0)" ::: "memory");
    BAR();

    // epilogue: C/D layout col=lane&15, row=(lane>>4)*4+reg
    const int r0 = i0 + wm * 128 + q4 * 4;
    const int c0 = o0 + wn * 64 + m16;
#pragma unroll
    for (int mf = 0; mf < 8; ++mf) {
#pragma unroll
        for (int rr = 0; rr < 4; ++rr) {
            const size_t row = r0 + mf * 16 + rr;
#pragma unroll
            for (int nf = 0; nf < 4; ++nf) {
                const size_t col = c0 + nf * 16;
                float v = acc[mf][nf][rr];
                if (MODE == 0) {
                    Cf[row * (size_t)N + col] = v;
                } else {  // MODE 4: paired swiglu (even col = gate, odd = up)
                    float pv = __shfl_xor(v, 1, 64);
                    if (!(l & 1)) {
                        float res = v / (1.f + __expf(-v)) * pv;
                        Cb[row * (size_t)(N >> 1) + (col >> 1)] = f2bf(res);
                    }
                }
            }
        }
    }
}

// ---------------- flash attention (MFMA): one block per (b,h,64-row q-tile) ----
__global__ __launch_bounds__(256) void k_fattn(const ushort_t* __restrict__ qkv,
                                               const ushort_t* __restrict__ hn,
                                               const float* __restrict__ alpha,
                                               ushort_t* __restrict__ out) {
    __shared__ ushort_t Ks[64][72];
    __shared__ ushort_t Vt[64][72];
    __shared__ ushort_t Ps[4][16][72];

    const int bid = blockIdx.x;
    const int bh  = bid & 31;           // b*16 + h
    const int qt  = 15 - (bid >> 5);    // heavy q-tiles dispatched first
    const int hh  = bh & 15;
    const int b   = bh >> 4;
    const int tid = threadIdx.x;
    const int wm  = tid >> 6;
    const int ln  = tid & 63;
    const int m16 = ln & 15;
    const int q4  = ln >> 4;

    const int bS0 = b * SS;
    const int q0  = qt * 64 + wm * 16;

    bf16x8 qa0, qa1;
    {
        const ushort_t* qp = qkv + (size_t)(bS0 + q0 + m16) * 3072 + hh * DHH + q4 * 8;
        qa0 = __builtin_bit_cast(bf16x8, *(const ushort8v*)(qp));
        qa1 = __builtin_bit_cast(bf16x8, *(const ushort8v*)(qp + 32));
    }

    f32x4 oacc[4] = {};
    float mrow[4] = {-1e30f, -1e30f, -1e30f, -1e30f};
    float lrow[4] = {0.f, 0.f, 0.f, 0.f};

    const int c0a = tid, c1a = tid + 256;
    const int r0a = c0a >> 3, cc0 = (c0a & 7) * 8;
    const int r1a = c1a >> 3, cc1 = (c1a & 7) * 8;

    for (int t = 0; t <= qt; ++t) {
        __syncthreads();
        {
            const size_t kbase = (size_t)(bS0 + t * 64) * 3072 + 1024 + hh * DHH;
            *(ushort8v*)&Ks[r0a][cc0] = *(const ushort8v*)(qkv + kbase + (size_t)r0a * 3072 + cc0);
            *(ushort8v*)&Ks[r1a][cc1] = *(const ushort8v*)(qkv + kbase + (size_t)r1a * 3072 + cc1);
            const size_t vbase = (size_t)(bS0 + t * 64) * 3072 + 2048 + hh * DHH;
            ushort8v v0 = *(const ushort8v*)(qkv + vbase + (size_t)r0a * 3072 + cc0);
#pragma unroll
            for (int j = 0; j < 8; ++j) Vt[cc0 + j][r0a] = v0[j];
            ushort8v v1 = *(const ushort8v*)(qkv + vbase + (size_t)r1a * 3072 + cc1);
#pragma unroll
            for (int j = 0; j < 8; ++j) Vt[cc1 + j][r1a] = v1[j];
        }
        __syncthreads();

        f32x4 sc[4];
#pragma unroll
        for (int nt = 0; nt < 4; ++nt) {
            bf16x8 kb0 = __builtin_bit_cast(bf16x8, *(const ushort8v*)&Ks[nt * 16 + m16][q4 * 8]);
            bf16x8 kb1 = __builtin_bit_cast(bf16x8, *(const ushort8v*)&Ks[nt * 16 + m16][32 + q4 * 8]);
            f32x4 z = {};
            z = __builtin_amdgcn_mfma_f32_16x16x32_bf16(qa0, kb0, z, 0, 0, 0);
            sc[nt] = __builtin_amdgcn_mfma_f32_16x16x32_bf16(qa1, kb1, z, 0, 0, 0);
        }

        const bool diag = (t == qt);
#pragma unroll
        for (int r = 0; r < 4; ++r) {
            float s0 = sc[0][r] * 0.125f;
            float s1 = sc[1][r] * 0.125f;
            float s2 = sc[2][r] * 0.125f;
            float s3 = sc[3][r] * 0.125f;
            if (diag) {
                const int rl = wm * 16 + q4 * 4 + r;
                if (m16      > rl) s0 = -1e30f;
                if (m16 + 16 > rl) s1 = -1e30f;
                if (m16 + 32 > rl) s2 = -1e30f;
                if (m16 + 48 > rl) s3 = -1e30f;
            }
            float tm = fmaxf(fmaxf(s0, s1), fmaxf(s2, s3));
            tm = fmaxf(tm, __shfl_xor(tm, 1, 64));
            tm = fmaxf(tm, __shfl_xor(tm, 2, 64));
            tm = fmaxf(tm, __shfl_xor(tm, 4, 64));
            tm = fmaxf(tm, __shfl_xor(tm, 8, 64));
            const float mnew = fmaxf(mrow[r], tm);
            const float corr = __expf(mrow[r] - mnew);
            const float e0 = __expf(s0 - mnew);
            const float e1 = __expf(s1 - mnew);
            const float e2 = __expf(s2 - mnew);
            const float e3 = __expf(s3 - mnew);
            float rs = e0 + e1 + e2 + e3;
            rs += __shfl_xor(rs, 1, 64);
            rs += __shfl_xor(rs, 2, 64);
            rs += __shfl_xor(rs, 4, 64);
            rs += __shfl_xor(rs, 8, 64);
            lrow[r] = lrow[r] * corr + rs;
            mrow[r] = mnew;
#pragma unroll
            for (int dt = 0; dt < 4; ++dt) oacc[dt][r] *= corr;
            const int pr = q4 * 4 + r;
            Ps[wm][pr][m16]      = f2bf(e0);
            Ps[wm][pr][m16 + 16] = f2bf(e1);
            Ps[wm][pr][m16 + 32] = f2bf(e2);
            Ps[wm][pr][m16 + 48] = f2bf(e3);
        }

#pragma unroll
        for (int ks = 0; ks < 2; ++ks) {
            bf16x8 pa = __builtin_bit_cast(bf16x8, *(const ushort8v*)&Ps[wm][m16][ks * 32 + q4 * 8]);
#pragma unroll
            for (int dt = 0; dt < 4; ++dt) {
                bf16x8 vb = __builtin_bit_cast(bf16x8, *(const ushort8v*)&Vt[dt * 16 + m16][ks * 32 + q4 * 8]);
                oacc[dt] = __builtin_amdgcn_mfma_f32_16x16x32_bf16(pa, vb, oacc[dt], 0, 0, 0);
            }
        }
    }

    const float al = alpha[hh];
#pragma unroll
    for (int r = 0; r < 4; ++r) {
        const float inv = 1.f / lrow[r];
        const size_t row = (size_t)(bS0 + q0 + q4 * 4 + r);
#pragma unroll
        for (int dt = 0; dt < 4; ++dt) {
            const size_t idx = row * DD + hh * DHH + dt * 16 + m16;
            out[idx] = f2bf(oacc[dt][r] * inv + al * bf2f(hn[idx]));
        }
    }
}

extern "C" void kernel_launch(void* const* d_in, const int* in_sizes, int n_in,
                              void* d_out, int out_size, void* d_ws, size_t ws_size,
                              hipStream_t stream) {
    const int*   ids   = (const int*)d_in[0];
    const int*   emb_t = (const int*)d_in[1];
    const float* emb_s = (const float*)d_in[2];
    const int*   qt    = (const int*)d_in[3];
    const float* qs    = (const float*)d_in[4];
    const int*   kt    = (const int*)d_in[5];
    const float* ks    = (const float*)d_in[6];
    const int*   vt    = (const int*)d_in[7];
    const float* vs    = (const float*)d_in[8];
    const int*   ot    = (const int*)d_in[9];
    const float* os    = (const float*)d_in[10];
    const int*   gatet = (const int*)d_in[11];
    const float* gates = (const float*)d_in[12];
    const int*   upt   = (const int*)d_in[13];
    const float* ups   = (const float*)d_in[14];
    const int*   downt = (const int*)d_in[15];
    const float* downs = (const float*)d_in[16];
    const float* wa    = (const float*)d_in[17];
    const float* wm    = (const float*)d_in[18];
    const float* alpha = (const float*)d_in[19];
    const float* wf    = (const float*)d_in[20];
    const int*   headt = (const int*)d_in[21];
    const float* heads = (const float*)d_in[22];

    // ---- workspace layout (byte offsets; region [0,75MB) is time-aliased) ----
    const size_t MB = 1ull << 20;
    char* wsb = (char*)d_ws;
    ushort_t* wbuf = (ushort_t*)(wsb);            // <= 65.6MB (head); 16.8MB (ffn)
    ushort_t* gb   = (ushort_t*)(wsb + 58 * MB);  // 16.8MB
    float*    x    = (float*)   (wsb + 75 * MB);  // 8.4MB
    ushort_t* h    = (ushort_t*)(wsb + 84 * MB);  // 4.2MB
    ushort_t* qkvb = (ushort_t*)(wsb + 89 * MB);  // 12.6MB  [BSR, 3072]
    ushort_t* ao   = (ushort_t*)(wsb + 102 * MB); // 4.2MB   ends ~106.2MB

    const size_t wDD = (size_t)DD * DD;
    const size_t sDD = wDD / GSZ;
    const size_t wFD = (size_t)DFFD * DD;
    const size_t sFD = wFD / GSZ;

    k_embed<<<BSR, 256, 0, stream>>>(ids, emb_t, emb_s, x);

    for (int l = 0; l < LL; ++l) {
        k_rmsnorm<<<BSR, 256, 0, stream>>>(x, wa + l * DD, h);
        k_dequant<<<wDD / 1024, 256, 0, stream>>>(qt + l * wDD, qs + l * sDD, wbuf);
        k_dequant<<<wDD / 1024, 256, 0, stream>>>(kt + l * wDD, ks + l * sDD, wbuf + wDD);
        k_dequant<<<wDD / 1024, 256, 0, stream>>>(vt + l * wDD, vs + l * sDD, wbuf + 2 * wDD);
        gemm_bf16<3><<<24 * 16, 256, 0, stream>>>(h, wbuf, nullptr, qkvb, BSR, 3072, DD);
        k_fattn<<<16 * BB * HH, 256, 0, stream>>>(qkvb, h, alpha + l * HH, ao);
        k_dequant<<<wDD / 1024, 256, 0, stream>>>(ot + l * wDD, os + l * sDD, wbuf);
        gemm_bf16<1><<<8 * 16, 256, 0, stream>>>(ao, wbuf, x, nullptr, BSR, DD, DD);

        k_rmsnorm<<<BSR, 256, 0, stream>>>(x, wm + l * DD, h);
        k_dequant_il<<<wFD / 1024, 256, 0, stream>>>(gatet + l * wFD, gates + l * sFD, wbuf, 0);
        k_dequant_il<<<wFD / 1024, 256, 0, stream>>>(upt + l * wFD, ups + l * sFD, wbuf, 1);
        gemm256<4><<<32 * 8, 512, 0, stream>>>(h, wbuf, nullptr, gb, 8192, DD);
        k_dequant<<<wFD / 1024, 256, 0, stream>>>(downt + l * wFD, downs + l * sFD, wbuf);
        gemm_bf16<1><<<8 * 16, 256, 0, stream>>>(gb, wbuf, x, nullptr, BSR, DD, DFFD);
    }

    k_rmsnorm<<<BSR, 256, 0, stream>>>(x, wf, h);
    k_dequant<<<((size_t)VV * DD) / 1024, 256, 0, stream>>>(headt, heads, wbuf);
    gemm256<0><<<125 * 8, 512, 0, stream>>>(h, wbuf, (float*)d_out, nullptr, VV, DD);
}

// Round 6
// 1125.444 us; speedup vs baseline: 1.9932x; 1.0097x over previous
//
#include <hip/hip_runtime.h>
#include <math.h>
#include <stdint.h>

// dims
#define BB   2
#define SS   1024
#define DD   1024
#define HH   16
#define DHH  64
#define DFFD 4096
#define LL   2
#define VV   32000
#define GSZ  128
#define BSR  (BB*SS)   // 2048 rows
constexpr float EPS = 1e-6f;

typedef unsigned short ushort_t;
typedef __bf16 bf16x8 __attribute__((ext_vector_type(8)));
typedef short  short8 __attribute__((ext_vector_type(8)));
typedef unsigned short ushort8v __attribute__((ext_vector_type(8)));
typedef float  f32x4  __attribute__((ext_vector_type(4)));

__device__ inline ushort_t f2bf(float f) {
    unsigned int u = __builtin_bit_cast(unsigned int, f);
    unsigned int r = u + 0x7fffu + ((u >> 16) & 1u);
    return (ushort_t)(r >> 16);
}
__device__ inline float bf2f(ushort_t u) {
    unsigned int x = ((unsigned int)u) << 16;
    return __builtin_bit_cast(float, x);
}

#define GL2L(g, l) __builtin_amdgcn_global_load_lds( \
    (const __attribute__((address_space(1))) void*)(g), \
    (__attribute__((address_space(3))) void*)(l), 16, 0, 0)

// ---------------- dequant: W[i] = bf16(T[i] * S[i/128]) ----------------
__global__ __launch_bounds__(256) void k_dequant(const int* __restrict__ T,
                                                 const float* __restrict__ S,
                                                 ushort_t* __restrict__ W) {
    int i = (blockIdx.x * 256 + threadIdx.x) * 4;
    int4 t = *(const int4*)(T + i);
    float s = S[i >> 7];
    ushort4 w;
    w.x = f2bf((float)t.x * s); w.y = f2bf((float)t.y * s);
    w.z = f2bf((float)t.z * s); w.w = f2bf((float)t.w * s);
    *(ushort4*)(W + i) = w;
}

// fused 3-tensor dequant (qkv): blockIdx.y selects tensor, dest stacked
__global__ __launch_bounds__(256) void k_dequant3(const int* __restrict__ T0,
                                                  const int* __restrict__ T1,
                                                  const int* __restrict__ T2,
                                                  const float* __restrict__ S0,
                                                  const float* __restrict__ S1,
                                                  const float* __restrict__ S2,
                                                  ushort_t* __restrict__ W) {
    const int* T; const float* S; ushort_t* Wd;
    const size_t n = (size_t)DD * DD;
    if (blockIdx.y == 0)      { T = T0; S = S0; Wd = W; }
    else if (blockIdx.y == 1) { T = T1; S = S1; Wd = W + n; }
    else                      { T = T2; S = S2; Wd = W + 2 * n; }
    int i = (blockIdx.x * 256 + threadIdx.x) * 4;
    int4 t = *(const int4*)(T + i);
    float s = S[i >> 7];
    ushort4 w;
    w.x = f2bf((float)t.x * s); w.y = f2bf((float)t.y * s);
    w.z = f2bf((float)t.z * s); w.w = f2bf((float)t.w * s);
    *(ushort4*)(Wd + i) = w;
}

// fused gate/up dequant with row interleave: tensor y, source row r -> dest 2r+y
__global__ __launch_bounds__(256) void k_dequant_il2(const int* __restrict__ T0,
                                                     const int* __restrict__ T1,
                                                     const float* __restrict__ S0,
                                                     const float* __restrict__ S1,
                                                     ushort_t* __restrict__ W) {
    const int which = blockIdx.y;
    const int* T = which ? T1 : T0;
    const float* S = which ? S1 : S0;
    int i = (blockIdx.x * 256 + threadIdx.x) * 4;
    int4 t = *(const int4*)(T + i);
    float s = S[i >> 7];
    ushort4 w;
    w.x = f2bf((float)t.x * s); w.y = f2bf((float)t.y * s);
    w.z = f2bf((float)t.z * s); w.w = f2bf((float)t.w * s);
    int r = i >> 10, c = i & 1023;
    *(ushort4*)(W + (((size_t)((r << 1) | which)) << 10) + c) = w;
}

// ---------------- embedding ----------------
__global__ __launch_bounds__(256) void k_embed(const int* __restrict__ ids,
                                               const int* __restrict__ t,
                                               const float* __restrict__ s,
                                               float* __restrict__ x) {
    int row = blockIdx.x;
    int id  = ids[row];
    for (int d = threadIdx.x; d < DD; d += 256) {
        x[(size_t)row * DD + d] =
            (float)t[(size_t)id * DD + d] * s[id * (DD / GSZ) + (d >> 7)];
    }
}

// ---------------- rmsnorm ----------------
__global__ __launch_bounds__(256) void k_rmsnorm(const float* __restrict__ x,
                                                 const float* __restrict__ w,
                                                 ushort_t* __restrict__ o) {
    int row = blockIdx.x;
    const float* xr = x + (size_t)row * DD;
    float ss = 0.f;
    for (int d = threadIdx.x; d < DD; d += 256) { float v = xr[d]; ss += v * v; }
    __shared__ float sm[4];
    for (int off = 32; off > 0; off >>= 1) ss += __shfl_down(ss, off, 64);
    if ((threadIdx.x & 63) == 0) sm[threadIdx.x >> 6] = ss;
    __syncthreads();
    float tot = sm[0] + sm[1] + sm[2] + sm[3];
    float inv = rsqrtf(tot / DD + EPS);
    for (int d = threadIdx.x; d < DD; d += 256)
        o[(size_t)row * DD + d] = f2bf(xr[d] * inv * w[d]);
}

// ---------------- 128x128 bf16 MFMA GEMM (m97 structure) ----------------
// MODE: 1 = add f32, 3 = store bf16
template <int MODE>
__global__ __launch_bounds__(256) void gemm_bf16(const ushort_t* __restrict__ A,
                                                 const ushort_t* __restrict__ W,
                                                 float* __restrict__ Cf,
                                                 ushort_t* __restrict__ Cb,
                                                 int M, int N, int K) {
    __shared__ ushort_t As[128 * 32];
    __shared__ ushort_t Bs[128 * 32];
    const int tid  = threadIdx.x;
    const int wave = tid >> 6, lane = tid & 63;
    const int wm = wave >> 1, wn = wave & 1;

    const int nwg  = gridDim.x;
    const int orig = blockIdx.x;
    const int wgid = (orig & 7) * (nwg >> 3) + (orig >> 3);   // XCD-bijective
    const int i0 = (wgid & 15) * 128;                          // y-fast
    const int o0 = (wgid >> 4) * 128;

    f32x4 acc[4][4] = {};

    const int srow = wave * 32 + (lane >> 2);
    const int scol = (lane & 3) * 8;
    const ushort_t* aG0 = A + (size_t)(i0 + srow) * K + scol;
    const ushort_t* aG1 = aG0 + (size_t)16 * K;
    const ushort_t* bG0 = W + (size_t)(o0 + srow) * K + scol;
    const ushort_t* bG1 = bG0 + (size_t)16 * K;
    ushort_t* aL0 = As + wave * 1024;
    ushort_t* aL1 = aL0 + 512;
    ushort_t* bL0 = Bs + wave * 1024;
    ushort_t* bL1 = bL0 + 512;

    const ushort_t* ap = As + (wm * 64 + (lane & 15)) * 32 + (lane >> 4) * 8;
    const ushort_t* bp = Bs + (wn * 64 + (lane & 15)) * 32 + (lane >> 4) * 8;

    for (int k0 = 0; k0 < K; k0 += 32) {
        __syncthreads();
        GL2L(aG0 + k0, aL0);
        GL2L(aG1 + k0, aL1);
        GL2L(bG0 + k0, bL0);
        GL2L(bG1 + k0, bL1);
        __syncthreads();
        bf16x8 av[4], bv[4];
#pragma unroll
        for (int t = 0; t < 4; ++t) {
            av[t] = __builtin_bit_cast(bf16x8, *(const short8*)(ap + t * 512));
            bv[t] = __builtin_bit_cast(bf16x8, *(const short8*)(bp + t * 512));
        }
#pragma unroll
        for (int mt = 0; mt < 4; ++mt)
#pragma unroll
            for (int nt = 0; nt < 4; ++nt)
                acc[mt][nt] = __builtin_amdgcn_mfma_f32_16x16x32_bf16(
                    av[mt], bv[nt], acc[mt][nt], 0, 0, 0);
    }

    const int r0 = wm * 64 + (lane >> 4) * 4;
    const int c0 = wn * 64 + (lane & 15);
#pragma unroll
    for (int mt = 0; mt < 4; ++mt) {
#pragma unroll
        for (int r = 0; r < 4; ++r) {
            const size_t row = i0 + r0 + mt * 16 + r;
#pragma unroll
            for (int nt = 0; nt < 4; ++nt) {
                const size_t col = o0 + c0 + nt * 16;
                const size_t idx = row * (size_t)N + col;
                float v = acc[mt][nt][r];
                if (MODE == 1) Cf[idx] += v;
                else           Cb[idx] = f2bf(v);
            }
        }
    }
}

// ---------------- 256x256 8-phase bf16 MFMA GEMM (T2+T3+T4+T5) ----------------
#define BAR()    __builtin_amdgcn_s_barrier()
#define WAITL0() do { asm volatile("s_waitcnt lgkmcnt(0)" ::: "memory"); \
                      __builtin_amdgcn_sched_barrier(0); } while (0)
#define WAITV4() asm volatile("s_waitcnt vmcnt(4)" ::: "memory")

#define STG(gbase, sbase, tile, half, call) do {                          \
    int _ko = (tile) * 64; if (_ko > K - 64) _ko = K - 64;                \
    GL2L((gbase) + (size_t)((half) * 128 + (call) * 64) * K + _ko,        \
         (sbase) + (half) * 8192 + (call) * 4096); } while (0)

#define RD_B(so) do { _Pragma("unroll") for (int nf = 0; nf < 4; ++nf) {  \
    bfr[nf][0] = __builtin_bit_cast(bf16x8, *(const short8*)(rB + (so) + nf * 1024 + colA0)); \
    bfr[nf][1] = __builtin_bit_cast(bf16x8, *(const short8*)(rB + (so) + nf * 1024 + colA1)); } } while (0)

#define RD_A(so, mf0) do { _Pragma("unroll") for (int i = 0; i < 2; ++i) { \
    afr[i][0] = __builtin_bit_cast(bf16x8, *(const short8*)(rA + (so) + ((mf0) + i) * 1024 + colA0)); \
    afr[i][1] = __builtin_bit_cast(bf16x8, *(const short8*)(rA + (so) + ((mf0) + i) * 1024 + colA1)); } } while (0)

#define MFMA16(mf0) do {                                                   \
    __builtin_amdgcn_s_setprio(1);                                         \
    _Pragma("unroll") for (int i = 0; i < 2; ++i)                          \
    _Pragma("unroll") for (int nf = 0; nf < 4; ++nf) {                     \
        acc[(mf0) + i][nf] = __builtin_amdgcn_mfma_f32_16x16x32_bf16(      \
            afr[i][0], bfr[nf][0], acc[(mf0) + i][nf], 0, 0, 0);           \
        acc[(mf0) + i][nf] = __builtin_amdgcn_mfma_f32_16x16x32_bf16(      \
            afr[i][1], bfr[nf][1], acc[(mf0) + i][nf], 0, 0, 0); }         \
    __builtin_amdgcn_s_setprio(0); } while (0)

template <int MODE>
__global__ __launch_bounds__(512, 2) void gemm256(const ushort_t* __restrict__ A,
                                                  const ushort_t* __restrict__ W,
                                                  float* __restrict__ Cf,
                                                  ushort_t* __restrict__ Cb,
                                                  int N, int K) {
    __shared__ ushort_t smem[65536];   // A0 | A1 | B0 | B1, 16384 ushorts each

    const int tid = threadIdx.x;
    const int w   = tid >> 6;
    const int l   = tid & 63;
    const int wm  = w >> 2;
    const int wn  = w & 3;
    const int m16 = l & 15;
    const int q4  = l >> 4;

    const int nwg  = gridDim.x;
    const int orig = blockIdx.x;
    const int wgid = (orig & 7) * (nwg >> 3) + (orig >> 3);   // XCD-bijective
    const int i0   = (wgid & 7) * 256;                         // y-fast (M=2048)
    const int o0   = (wgid >> 3) * 256;

    const int sc = (((l & 7) ^ (l >> 3)) * 8);
    const int srow = w * 8 + (l >> 3);
    const ushort_t* gA = A + (size_t)(i0 + srow) * K + sc;
    const ushort_t* gB = W + (size_t)(o0 + srow) * K + sc;
    ushort_t* sA0 = smem + w * 512;
    ushort_t* sA1 = sA0 + 16384;
    ushort_t* sB0 = sA0 + 32768;
    ushort_t* sB1 = sA0 + 49152;

    const int colA0 = ((q4 ^ (m16 & 7)) * 8);
    const int colA1 = colA0 ^ 32;
    const ushort_t* rA = smem + (wm * 128 + m16) * 64;
    const ushort_t* rB = smem + 32768 + (wn * 64 + m16) * 64;

    f32x4 acc[8][4] = {};
    bf16x8 bfr[4][2];
    bf16x8 afr[2][2];

    STG(gB, sB0, 0, 0, 0); STG(gB, sB0, 0, 0, 1);
    STG(gB, sB0, 0, 1, 0); STG(gB, sB0, 0, 1, 1);
    STG(gA, sA0, 0, 0, 0); STG(gA, sA0, 0, 0, 1);
    STG(gA, sA0, 0, 1, 0); STG(gA, sA0, 0, 1, 1);
    STG(gB, sB1, 1, 0, 0); STG(gB, sB1, 1, 0, 1);
    STG(gB, sB1, 1, 1, 0); STG(gB, sB1, 1, 1, 1);
    WAITV4();
    BAR();

    const int niter = K >> 7;
    for (int it = 0; it < niter; ++it) {
        const int t0 = it * 2;
        RD_B(0); RD_A(0, 0);
        STG(gA, sA1, t0 + 1, 0, 0); STG(gA, sA1, t0 + 1, 0, 1);
        STG(gA, sA1, t0 + 1, 1, 0); STG(gA, sA1, t0 + 1, 1, 1);
        BAR(); WAITL0(); MFMA16(0); BAR();
        RD_A(0, 2);
        STG(gB, sB0, t0 + 2, 0, 0); STG(gB, sB0, t0 + 2, 0, 1);
        BAR(); WAITL0(); MFMA16(2); BAR();
        RD_A(0, 4);
        STG(gB, sB0, t0 + 2, 1, 0); STG(gB, sB0, t0 + 2, 1, 1);
        BAR(); WAITL0(); MFMA16(4); BAR();
        RD_A(0, 6);
        BAR(); WAITL0(); MFMA16(6);
        WAITV4(); BAR();
        RD_B(16384); RD_A(16384, 0);
        STG(gA, sA0, t0 + 2, 0, 0); STG(gA, sA0, t0 + 2, 0, 1);
        BAR(); WAITL0(); MFMA16(0); BAR();
        RD_A(16384, 2);
        STG(gA, sA0, t0 + 2, 1, 0); STG(gA, sA0, t0 + 2, 1, 1);
        BAR(); WAITL0(); MFMA16(2); BAR();
        RD_A(16384, 4);
        STG(gB, sB1, t0 + 3, 0, 0); STG(gB, sB1, t0 + 3, 0, 1);
        BAR(); WAITL0(); MFMA16(4); BAR();
        RD_A(16384, 6);
        STG(gB, sB1, t0 + 3, 1, 0); STG(gB, sB1, t0 + 3, 1, 1);
        BAR(); WAITL0(); MFMA16(6);
        WAITV4(); BAR();
    }

    asm volatile("s_waitcnt vmcnt(0) lgkmcnt(0)" ::: "memory");
    BAR();

    const int r0 = i0 + wm * 128 + q4 * 4;
    const int c0 = o0 + wn * 64 + m16;
#pragma unroll
    for (int mf = 0; mf < 8; ++mf) {
#pragma unroll
        for (int rr = 0; rr < 4; ++rr) {
            const size_t row = r0 + mf * 16 + rr;
#pragma unroll
            for (int nf = 0; nf < 4; ++nf) {
                const size_t col = c0 + nf * 16;
                float v = acc[mf][nf][rr];
                if (MODE == 0) {
                    Cf[row * (size_t)N + col] = v;
                } else {  // MODE 4: paired swiglu (even col = gate, odd = up)
                    float pv = __shfl_xor(v, 1, 64);
                    if (!(l & 1)) {
                        float res = v / (1.f + __expf(-v)) * pv;
                        Cb[row * (size_t)(N >> 1) + (col >> 1)] = f2bf(res);
                    }
                }
            }
        }
    }
}

// ---------------- flash attention (MFMA): one block per (b,h,64-row q-tile) ----
// T2 swizzles (pitch 64, 128B rows):
//   Ks[key][dh]: phys col = dh ^ 8*(key&7)           (conflict-free store, floor read)
//   Vt[dh][key]: phys col = key ^ 8*(((dh>>3)^dh)&7) (conflict-free transpose store,
//                                                      floor-class PV read)
__global__ __launch_bounds__(256) void k_fattn(const ushort_t* __restrict__ qkv,
                                               const ushort_t* __restrict__ hn,
                                               const float* __restrict__ alpha,
                                               ushort_t* __restrict__ out) {
    __shared__ ushort_t Ks[64][64];
    __shared__ ushort_t Vt[64][64];
    __shared__ ushort_t Ps[4][16][72];

    const int bid = blockIdx.x;
    const int bh  = bid & 31;           // b*16 + h
    const int qt  = 15 - (bid >> 5);    // heavy q-tiles dispatched first
    const int hh  = bh & 15;
    const int b   = bh >> 4;
    const int tid = threadIdx.x;
    const int wm  = tid >> 6;
    const int ln  = tid & 63;
    const int m16 = ln & 15;
    const int q4  = ln >> 4;

    const int bS0 = b * SS;
    const int q0  = qt * 64 + wm * 16;

    bf16x8 qa0, qa1;
    {
        const ushort_t* qp = qkv + (size_t)(bS0 + q0 + m16) * 3072 + hh * DHH + q4 * 8;
        qa0 = __builtin_bit_cast(bf16x8, *(const ushort8v*)(qp));
        qa1 = __builtin_bit_cast(bf16x8, *(const ushort8v*)(qp + 32));
    }

    f32x4 oacc[4] = {};
    float mrow[4] = {-1e30f, -1e30f, -1e30f, -1e30f};
    float lrow[4] = {0.f, 0.f, 0.f, 0.f};

    const int u8  = tid & 7;            // staging col-chunk (dh/8 for V, dh cols for K)
    const int r0a = tid >> 3;           // staging row 0..31
    const int r1a = r0a + 32;           // staging row 32..63
    const int cc0 = u8 * 8;

    // K-read swizzled cols (per nt: row = nt*16+m16 -> key&7 = m16&7)
    const int k7   = m16 & 7;
    const int kc0  = (q4 ^ k7) * 8;
    const int kc1  = ((q4 + 4) ^ k7) * 8;

    for (int t = 0; t <= qt; ++t) {
        __syncthreads();
        {
            const size_t kbase = (size_t)(bS0 + t * 64) * 3072 + 1024 + hh * DHH;
            *(ushort8v*)&Ks[r0a][cc0 ^ ((r0a & 7) * 8)] =
                *(const ushort8v*)(qkv + kbase + (size_t)r0a * 3072 + cc0);
            *(ushort8v*)&Ks[r1a][cc0 ^ ((r1a & 7) * 8)] =
                *(const ushort8v*)(qkv + kbase + (size_t)r1a * 3072 + cc0);
            const size_t vbase = (size_t)(bS0 + t * 64) * 3072 + 2048 + hh * DHH;
            ushort8v v0 = *(const ushort8v*)(qkv + vbase + (size_t)r0a * 3072 + cc0);
#pragma unroll
            for (int j = 0; j < 8; ++j) Vt[cc0 + j][r0a ^ ((u8 ^ j) * 8)] = v0[j];
            ushort8v v1 = *(const ushort8v*)(qkv + vbase + (size_t)r1a * 3072 + cc0);
#pragma unroll
            for (int j = 0; j < 8; ++j) Vt[cc0 + j][r1a ^ ((u8 ^ j) * 8)] = v1[j];
        }
        __syncthreads();

        f32x4 sc[4];
#pragma unroll
        for (int nt = 0; nt < 4; ++nt) {
            bf16x8 kb0 = __builtin_bit_cast(bf16x8, *(const ushort8v*)&Ks[nt * 16 + m16][kc0]);
            bf16x8 kb1 = __builtin_bit_cast(bf16x8, *(const ushort8v*)&Ks[nt * 16 + m16][kc1]);
            f32x4 z = {};
            z = __builtin_amdgcn_mfma_f32_16x16x32_bf16(qa0, kb0, z, 0, 0, 0);
            sc[nt] = __builtin_amdgcn_mfma_f32_16x16x32_bf16(qa1, kb1, z, 0, 0, 0);
        }

        const bool diag = (t == qt);
#pragma unroll
        for (int r = 0; r < 4; ++r) {
            float s0 = sc[0][r] * 0.125f;
            float s1 = sc[1][r] * 0.125f;
            float s2 = sc[2][r] * 0.125f;
            float s3 = sc[3][r] * 0.125f;
            if (diag) {
                const int rl = wm * 16 + q4 * 4 + r;
                if (m16      > rl) s0 = -1e30f;
                if (m16 + 16 > rl) s1 = -1e30f;
                if (m16 + 32 > rl) s2 = -1e30f;
                if (m16 + 48 > rl) s3 = -1e30f;
            }
            float tm = fmaxf(fmaxf(s0, s1), fmaxf(s2, s3));
            tm = fmaxf(tm, __shfl_xor(tm, 1, 64));
            tm = fmaxf(tm, __shfl_xor(tm, 2, 64));
            tm = fmaxf(tm, __shfl_xor(tm, 4, 64));
            tm = fmaxf(tm, __shfl_xor(tm, 8, 64));
            const float mnew = fmaxf(mrow[r], tm);
            const float corr = __expf(mrow[r] - mnew);
            const float e0 = __expf(s0 - mnew);
            const float e1 = __expf(s1 - mnew);
            const float e2 = __expf(s2 - mnew);
            const float e3 = __expf(s3 - mnew);
            float rs = e0 + e1 + e2 + e3;
            rs += __shfl_xor(rs, 1, 64);
            rs += __shfl_xor(rs, 2, 64);
            rs += __shfl_xor(rs, 4, 64);
            rs += __shfl_xor(rs, 8, 64);
            lrow[r] = lrow[r] * corr + rs;
            mrow[r] = mnew;
#pragma unroll
            for (int dt = 0; dt < 4; ++dt) oacc[dt][r] *= corr;
            const int pr = q4 * 4 + r;
            Ps[wm][pr][m16]      = f2bf(e0);
            Ps[wm][pr][m16 + 16] = f2bf(e1);
            Ps[wm][pr][m16 + 32] = f2bf(e2);
            Ps[wm][pr][m16 + 48] = f2bf(e3);
        }

#pragma unroll
        for (int ks = 0; ks < 2; ++ks) {
            bf16x8 pa = __builtin_bit_cast(bf16x8, *(const ushort8v*)&Ps[wm][m16][ks * 32 + q4 * 8]);
#pragma unroll
            for (int dt = 0; dt < 4; ++dt) {
                const int dh = dt * 16 + m16;
                const int vg = ((dh >> 3) ^ dh) & 7;
                bf16x8 vb = __builtin_bit_cast(bf16x8,
                    *(const ushort8v*)&Vt[dh][((ks * 4 + q4) ^ vg) * 8]);
                oacc[dt] = __builtin_amdgcn_mfma_f32_16x16x32_bf16(pa, vb, oacc[dt], 0, 0, 0);
            }
        }
    }

    const float al = alpha[hh];
#pragma unroll
    for (int r = 0; r < 4; ++r) {
        const float inv = 1.f / lrow[r];
        const size_t row = (size_t)(bS0 + q0 + q4 * 4 + r);
#pragma unroll
        for (int dt = 0; dt < 4; ++dt) {
            const size_t idx = row * DD + hh * DHH + dt * 16 + m16;
            out[idx] = f2bf(oacc[dt][r] * inv + al * bf2f(hn[idx]));
        }
    }
}

extern "C" void kernel_launch(void* const* d_in, const int* in_sizes, int n_in,
                              void* d_out, int out_size, void* d_ws, size_t ws_size,
                              hipStream_t stream) {
    const int*   ids   = (const int*)d_in[0];
    const int*   emb_t = (const int*)d_in[1];
    const float* emb_s = (const float*)d_in[2];
    const int*   qt    = (const int*)d_in[3];
    const float* qs    = (const float*)d_in[4];
    const int*   kt    = (const int*)d_in[5];
    const float* ks    = (const float*)d_in[6];
    const int*   vt    = (const int*)d_in[7];
    const float* vs    = (const float*)d_in[8];
    const int*   ot    = (const int*)d_in[9];
    const float* os    = (const float*)d_in[10];
    const int*   gatet = (const int*)d_in[11];
    const float* gates = (const float*)d_in[12];
    const int*   upt   = (const int*)d_in[13];
    const float* ups   = (const float*)d_in[14];
    const int*   downt = (const int*)d_in[15];
    const float* downs = (const float*)d_in[16];
    const float* wa    = (const float*)d_in[17];
    const float* wm    = (const float*)d_in[18];
    const float* alpha = (const float*)d_in[19];
    const float* wf    = (const float*)d_in[20];
    const int*   headt = (const int*)d_in[21];
    const float* heads = (const float*)d_in[22];

    // ---- workspace layout (byte offsets; region [0,75MB) is time-aliased) ----
    const size_t MB = 1ull << 20;
    char* wsb = (char*)d_ws;
    ushort_t* wbuf = (ushort_t*)(wsb);            // <= 65.6MB (head); 16.8MB (ffn)
    ushort_t* gb   = (ushort_t*)(wsb + 58 * MB);  // 16.8MB
    float*    x    = (float*)   (wsb + 75 * MB);  // 8.4MB
    ushort_t* h    = (ushort_t*)(wsb + 84 * MB);  // 4.2MB
    ushort_t* qkvb = (ushort_t*)(wsb + 89 * MB);  // 12.6MB  [BSR, 3072]
    ushort_t* ao   = (ushort_t*)(wsb + 102 * MB); // 4.2MB   ends ~106.2MB

    const size_t wDD = (size_t)DD * DD;
    const size_t sDD = wDD / GSZ;
    const size_t wFD = (size_t)DFFD * DD;
    const size_t sFD = wFD / GSZ;

    k_embed<<<BSR, 256, 0, stream>>>(ids, emb_t, emb_s, x);

    for (int l = 0; l < LL; ++l) {
        k_rmsnorm<<<BSR, 256, 0, stream>>>(x, wa + l * DD, h);
        k_dequant3<<<dim3(wDD / 1024, 3), 256, 0, stream>>>(
            qt + l * wDD, kt + l * wDD, vt + l * wDD,
            qs + l * sDD, ks + l * sDD, vs + l * sDD, wbuf);
        gemm_bf16<3><<<24 * 16, 256, 0, stream>>>(h, wbuf, nullptr, qkvb, BSR, 3072, DD);
        k_fattn<<<16 * BB * HH, 256, 0, stream>>>(qkvb, h, alpha + l * HH, ao);
        k_dequant<<<wDD / 1024, 256, 0, stream>>>(ot + l * wDD, os + l * sDD, wbuf);
        gemm_bf16<1><<<8 * 16, 256, 0, stream>>>(ao, wbuf, x, nullptr, BSR, DD, DD);

        k_rmsnorm<<<BSR, 256, 0, stream>>>(x, wm + l * DD, h);
        k_dequant_il2<<<dim3(wFD / 1024, 2), 256, 0, stream>>>(
            gatet + l * wFD, upt + l * wFD,
            gates + l * sFD, ups + l * sFD, wbuf);
        gemm256<4><<<32 * 8, 512, 0, stream>>>(h, wbuf, nullptr, gb, 8192, DD);
        k_dequant<<<wFD / 1024, 256, 0, stream>>>(downt + l * wFD, downs + l * sFD, wbuf);
        gemm_bf16<1><<<8 * 16, 256, 0, stream>>>(gb, wbuf, x, nullptr, BSR, DD, DFFD);
    }

    k_rmsnorm<<<BSR, 256, 0, stream>>>(x, wf, h);
    k_dequant<<<((size_t)VV * DD) / 1024, 256, 0, stream>>>(headt, heads, wbuf);
    gemm256<0><<<125 * 8, 512, 0, stream>>>(h, wbuf, (float*)d_out, nullptr, VV, DD);
}